// Round 2
// baseline (1022.486 us; speedup 1.0000x reference)
//
#include <hip/hip_runtime.h>

// Problem constants: B=4, L=256, E=2 (both ensembles), D=512, H=8, dk=dv=64, KG=16.
// All fp32. Workspace layout (floats, 1M = 1048576):
//   qp:0  qp2:1M  kp:2M  kp2:3M  vp:4M  pre:5M  fcb:6M  scores:7M..15M
// Total ws requirement: 15*1048576*4 = 62.9 MB.

static __device__ __forceinline__ float4 ld4(const float* p) {
    return *reinterpret_cast<const float4*>(p);
}

// ---------------------------------------------------------------------------
// K1/K6: generic tiled GEMM, 64x64 tile, BK=16, 256 threads, 4x4 per thread.
// M=1024 rows (b*256+l), K=512, N=512. A row pointer = A + m*1024 + ens*512.
// mode 0: qp/kp-style output [ (b*2+ens)*8+h ][ l ][ d ]   (h=n>>6, d=n&63)
// mode 1: vp output          [ b*8+h ][ l*2+ens ][ d ]
// mode 2: fc output          [ (m*2+ens) ][ n ]
// ---------------------------------------------------------------------------
__global__ __launch_bounds__(256) void gemm_k(
    const float* __restrict__ qin, const float* __restrict__ kin, const float* __restrict__ vin,
    const float* __restrict__ Wq, const float* __restrict__ Wk, const float* __restrict__ Wv,
    const float* __restrict__ Wq2, const float* __restrict__ Wk2,
    const float* __restrict__ prebuf, const float* __restrict__ Wfc,
    float* __restrict__ qp, float* __restrict__ qp2, float* __restrict__ kp,
    float* __restrict__ kp2, float* __restrict__ vp, float* __restrict__ fcb,
    int mm_base)
{
    __shared__ float As[64][17];   // pad 17: conflict-free column reads
    __shared__ float Bs[16][64];   // float4-aligned rows

    const int mm = mm_base + (int)blockIdx.z;
    const float* A; const float* W; float* Cb; int ens; int mode;
    switch (mm) {
        case 0:  A=qin;    W=Wq;           Cb=qp;  ens=0; mode=0; break;
        case 1:  A=qin;    W=Wq + 262144;  Cb=qp;  ens=1; mode=0; break;
        case 2:  A=qin;    W=Wq2;          Cb=qp2; ens=0; mode=0; break;
        case 3:  A=qin;    W=Wq2 + 262144; Cb=qp2; ens=1; mode=0; break;
        case 4:  A=kin;    W=Wk;           Cb=kp;  ens=0; mode=0; break;
        case 5:  A=kin;    W=Wk + 262144;  Cb=kp;  ens=1; mode=0; break;
        case 6:  A=kin;    W=Wk2;          Cb=kp2; ens=0; mode=0; break;
        case 7:  A=kin;    W=Wk2 + 262144; Cb=kp2; ens=1; mode=0; break;
        case 8:  A=vin;    W=Wv;           Cb=vp;  ens=0; mode=1; break;
        case 9:  A=vin;    W=Wv + 262144;  Cb=vp;  ens=1; mode=1; break;
        case 10: A=prebuf; W=Wfc;          Cb=fcb; ens=0; mode=2; break;
        default: A=prebuf; W=Wfc + 262144; Cb=fcb; ens=1; mode=2; break;
    }

    const int tid = threadIdx.x;
    const int m0 = blockIdx.y * 64;
    const int n0 = blockIdx.x * 64;
    const int ty = tid >> 4, tx = tid & 15;
    const int ar = tid >> 2, ac = (tid & 3) * 4;   // A tile: 64 rows x 16 k
    const int br = tid >> 4, bc = (tid & 15) * 4;  // B tile: 16 k x 64 n

    float acc[4][4] = {};

    for (int kt = 0; kt < 512; kt += 16) {
        float4 av = ld4(A + (size_t)(m0 + ar) * 1024 + ens * 512 + kt + ac);
        float4 bv = ld4(W + (size_t)(kt + br) * 512 + n0 + bc);
        __syncthreads();
        As[ar][ac + 0] = av.x; As[ar][ac + 1] = av.y;
        As[ar][ac + 2] = av.z; As[ar][ac + 3] = av.w;
        *reinterpret_cast<float4*>(&Bs[br][bc]) = bv;
        __syncthreads();
        #pragma unroll
        for (int kk = 0; kk < 16; ++kk) {
            float a0 = As[ty*4+0][kk];
            float a1 = As[ty*4+1][kk];
            float a2 = As[ty*4+2][kk];
            float a3 = As[ty*4+3][kk];
            float4 b4 = *reinterpret_cast<const float4*>(&Bs[kk][tx*4]);
            acc[0][0] += a0*b4.x; acc[0][1] += a0*b4.y; acc[0][2] += a0*b4.z; acc[0][3] += a0*b4.w;
            acc[1][0] += a1*b4.x; acc[1][1] += a1*b4.y; acc[1][2] += a1*b4.z; acc[1][3] += a1*b4.w;
            acc[2][0] += a2*b4.x; acc[2][1] += a2*b4.y; acc[2][2] += a2*b4.z; acc[2][3] += a2*b4.w;
            acc[3][0] += a3*b4.x; acc[3][1] += a3*b4.y; acc[3][2] += a3*b4.z; acc[3][3] += a3*b4.w;
        }
    }

    #pragma unroll
    for (int u = 0; u < 4; ++u) {
        const int m = m0 + ty * 4 + u;
        const int b = m >> 8, l = m & 255;
        #pragma unroll
        for (int w = 0; w < 4; ++w) {
            const int n = n0 + tx * 4 + w;
            const int h = n >> 6, d = n & 63;
            size_t dst;
            if (mode == 0)      dst = ((size_t)((b*2 + ens)*8 + h) * 256 + l) * 64 + d;
            else if (mode == 1) dst = ((size_t)(b*8 + h) * 512 + l*2 + ens) * 64 + d;
            else                dst = ((size_t)m*2 + ens) * 512 + n;
            Cb[dst] = acc[u][w];
        }
    }
}

// ---------------------------------------------------------------------------
// K2: gate MLP. One block = 64 consecutive (b,q,l) rows (same b,q) x 32 combos.
// Thread (bl,c): bl=tid>>5 (8 row-groups), c=tid&31 (combo (i*2+j)*8+h).
// Register-blocked: each thread holds 4 rows' t in VGPRs (2 passes of 4),
// so each w1 LDS read feeds 4 FMAs (LDS insts cut 4x vs row-serial version).
// Writes log_sigmoid(agg) directly into scores[bih][q][k*2+j] (K3 does RMW add).
// ---------------------------------------------------------------------------
__global__ __launch_bounds__(256) void mlp_k(
    const float* __restrict__ gr_mask, const int* __restrict__ mask,
    const float* __restrict__ grW1, const float* __restrict__ grb1,
    const float* __restrict__ grW2, const float* __restrict__ grb2,
    float* __restrict__ scores)
{
    __shared__ float w1s[256][33];  // [(g*16+m)][c], pad 33 -> conflict-free over c
    __shared__ float b1s[16][33];   // [m][c]
    __shared__ float w2s[16][33];   // [m][c]
    __shared__ float b2s[32];
    __shared__ float ts[64][17];    // [row_local][g]
    __shared__ float ls[64][33];    // [row_local][c] staging for coalesced writeout

    const int tid = threadIdx.x;
    const int row_base = blockIdx.x * 64;
    const int b  = row_base >> 16;
    const int q  = (row_base >> 8) & 255;
    const int l0 = row_base & 255;

    #pragma unroll
    for (int it = 0; it < 32; ++it) {               // grW1: 8192 = c*256 + g*16 + m
        int flat = tid + it * 256;
        w1s[flat & 255][flat >> 8] = grW1[flat];
    }
    #pragma unroll
    for (int it = 0; it < 2; ++it) {                // grb1 / grW2: 512 = c*16 + m
        int flat = tid + it * 256;
        b1s[flat & 15][flat >> 4] = grb1[flat];
        w2s[flat & 15][flat >> 4] = grW2[flat];
    }
    if (tid < 32) b2s[tid] = grb2[tid];
    #pragma unroll
    for (int it = 0; it < 4; ++it) {                // t[b,q,l,g] = gr_mask[b,g,q,l]
        int flat = tid + it * 256;                  // 64 rows x 16 g
        int g = flat >> 6, r = flat & 63;
        ts[r][g] = gr_mask[(size_t)(b*16 + g) * 65536 + q * 256 + l0 + r];
    }
    __syncthreads();

    const int bl = tid >> 5, c = tid & 31;
    #pragma unroll
    for (int p = 0; p < 2; ++p) {
        float tval[4][16];
        #pragma unroll
        for (int u = 0; u < 4; ++u)
            #pragma unroll
            for (int g = 0; g < 16; ++g) tval[u][g] = ts[bl*8 + p*4 + u][g];

        const float b2v = b2s[c];
        float agg0 = b2v, agg1 = b2v, agg2 = b2v, agg3 = b2v;
        #pragma unroll
        for (int m = 0; m < 16; ++m) {
            float bb = b1s[m][c];
            float a0 = bb, a1 = bb, a2 = bb, a3 = bb;
            #pragma unroll
            for (int g = 0; g < 16; ++g) {
                float w = w1s[g*16 + m][c];
                a0 += tval[0][g] * w;
                a1 += tval[1][g] * w;
                a2 += tval[2][g] * w;
                a3 += tval[3][g] * w;
            }
            float w2 = w2s[m][c];
            agg0 += fmaxf(a0, 0.f) * w2;
            agg1 += fmaxf(a1, 0.f) * w2;
            agg2 += fmaxf(a2, 0.f) * w2;
            agg3 += fmaxf(a3, 0.f) * w2;
        }
        float aggs[4] = {agg0, agg1, agg2, agg3};
        #pragma unroll
        for (int u = 0; u < 4; ++u) {
            const int rl = bl*8 + p*4 + u;
            float agv = aggs[u];
            if (mask[(size_t)(b*256 + q) * 256 + l0 + rl] == 0) agv = 0.f;
            // stable log-sigmoid
            ls[rl][c] = fminf(agv, 0.f) - log1pf(expf(-fabsf(agv)));
        }
    }
    __syncthreads();

    // writeout: scores[(((b*2+i)*8+h)*256+q)*512 + k*2 + j], k = l0+r2, c2=(i*2+j)*8+h
    #pragma unroll
    for (int it = 0; it < 8; ++it) {
        int flat = tid + it * 256;      // 32 c x 64 r
        int c2 = flat >> 6, r2 = flat & 63;
        int ii = c2 >> 4, jj = (c2 >> 3) & 1, hh = c2 & 7;
        size_t dst = ((size_t)((b*2 + ii)*8 + hh) * 256 + q) * 512 + (size_t)(l0 + r2) * 2 + jj;
        scores[dst] = ls[r2][c2];
    }
}

// ---------------------------------------------------------------------------
// K3: scores. Block: fixed (b,i,h,j), 32x32 (q,k) tile. s1/s2 dots over d=64,
// gate with tril(adj), add the staged log-sigmoid (RMW), apply mask.
// ---------------------------------------------------------------------------
__global__ __launch_bounds__(256) void scores_k(
    const float* __restrict__ qp, const float* __restrict__ qp2,
    const float* __restrict__ kp, const float* __restrict__ kp2,
    const float* __restrict__ adj, const int* __restrict__ mask,
    float* __restrict__ scores)
{
    __shared__ float q1s[32][65], q2s[32][65], k1s[32][65], k2s[32][65];

    const int z = blockIdx.z;
    const int bih = z >> 1, j = z & 1;
    const int b = bih >> 4, i = (bih >> 3) & 1, h = bih & 7;
    const int bjh = (b*2 + j)*8 + h;
    const int q0 = blockIdx.y * 32, k0 = blockIdx.x * 32;
    const int tid = threadIdx.x;

    const float* q1g = qp  + (size_t)bih * 16384 + q0 * 64;
    const float* q2g = qp2 + (size_t)bih * 16384 + q0 * 64;
    const float* k1g = kp  + (size_t)bjh * 16384 + k0 * 64;
    const float* k2g = kp2 + (size_t)bjh * 16384 + k0 * 64;
    #pragma unroll
    for (int it = 0; it < 2; ++it) {
        int idx4 = tid * 2 + it;            // 512 float4 per tile
        int r = idx4 >> 4, c4 = (idx4 & 15) * 4;
        float4 a = ld4(q1g + r*64 + c4);
        float4 e = ld4(q2g + r*64 + c4);
        float4 f = ld4(k1g + r*64 + c4);
        float4 g = ld4(k2g + r*64 + c4);
        q1s[r][c4+0]=a.x; q1s[r][c4+1]=a.y; q1s[r][c4+2]=a.z; q1s[r][c4+3]=a.w;
        q2s[r][c4+0]=e.x; q2s[r][c4+1]=e.y; q2s[r][c4+2]=e.z; q2s[r][c4+3]=e.w;
        k1s[r][c4+0]=f.x; k1s[r][c4+1]=f.y; k1s[r][c4+2]=f.z; k1s[r][c4+3]=f.w;
        k2s[r][c4+0]=g.x; k2s[r][c4+1]=g.y; k2s[r][c4+2]=g.z; k2s[r][c4+3]=g.w;
    }
    __syncthreads();

    const int tk = tid & 31, tq = tid >> 5;   // tq 0..7, 4 q-rows per thread
    float acc1[4] = {}, acc2[4] = {};
    for (int dd = 0; dd < 64; ++dd) {
        float kv1 = k1s[tk][dd], kv2 = k2s[tk][dd];
        #pragma unroll
        for (int u = 0; u < 4; ++u) {
            acc1[u] += q1s[tq*4 + u][dd] * kv1;
            acc2[u] += q2s[tq*4 + u][dd] * kv2;
        }
    }

    const int kg = k0 + tk;
    #pragma unroll
    for (int u = 0; u < 4; ++u) {
        const int qg = q0 + tq*4 + u;
        const size_t mi = (size_t)(b*256 + qg) * 256 + kg;
        float gate = (qg >= kg) ? adj[mi] : 0.f;   // tril includes diagonal
        float s = (acc1[u] * gate + acc2[u] * (1.f - gate)) * 0.125f; // /sqrt(64)
        const size_t sidx = ((size_t)bih * 256 + qg) * 512 + (size_t)kg * 2 + j;
        s += scores[sidx];                          // staged log-sigmoid term
        if (mask[mi] == 0) s = -1e9f;
        scores[sidx] = s;
    }
}

// ---------------------------------------------------------------------------
// K4: softmax over 512 (k,j) per row. 4 waves/block, one row per wave.
// ---------------------------------------------------------------------------
__global__ __launch_bounds__(256) void softmax_k(float* __restrict__ scores)
{
    const int row  = blockIdx.x * 4 + (threadIdx.x >> 6);
    const int lane = threadIdx.x & 63;
    float* p = scores + (size_t)row * 512 + lane * 8;
    float4 v0 = *reinterpret_cast<float4*>(p);
    float4 v1 = *reinterpret_cast<float4*>(p + 4);
    float v[8] = {v0.x, v0.y, v0.z, v0.w, v1.x, v1.y, v1.z, v1.w};

    float m = v[0];
    #pragma unroll
    for (int t = 1; t < 8; ++t) m = fmaxf(m, v[t]);
    #pragma unroll
    for (int off = 32; off > 0; off >>= 1) m = fmaxf(m, __shfl_xor(m, off));

    float s = 0.f;
    #pragma unroll
    for (int t = 0; t < 8; ++t) { v[t] = expf(v[t] - m); s += v[t]; }
    #pragma unroll
    for (int off = 32; off > 0; off >>= 1) s += __shfl_xor(s, off);

    const float inv = 1.f / s;
    v0 = make_float4(v[0]*inv, v[1]*inv, v[2]*inv, v[3]*inv);
    v1 = make_float4(v[4]*inv, v[5]*inv, v[6]*inv, v[7]*inv);
    *reinterpret_cast<float4*>(p)     = v0;
    *reinterpret_cast<float4*>(p + 4) = v1;
}

// ---------------------------------------------------------------------------
// K5: PV. Block: fixed (b,i,h), 32 q-rows. attn[256x512] @ vp[512x64].
// ---------------------------------------------------------------------------
__global__ __launch_bounds__(256) void pv_k(
    const float* __restrict__ attn, const float* __restrict__ vp,
    float* __restrict__ pre)
{
    __shared__ float as_[32][65];
    __shared__ float vs[64][65];

    const int bih = blockIdx.y;
    const int b = bih >> 4, i = (bih >> 3) & 1, h = bih & 7;
    const int q0 = blockIdx.x * 32;
    const int tid = threadIdx.x;
    const int d = tid & 63, qb = tid >> 6;   // qb 0..3, 8 q-rows per thread

    const float* ag = attn + ((size_t)bih * 256 + q0) * 512;
    const float* vg = vp + (size_t)(b*8 + h) * 32768;

    float acc[8] = {};
    for (int kc = 0; kc < 512; kc += 64) {
        __syncthreads();
        #pragma unroll
        for (int it = 0; it < 2; ++it) {         // attn 32x64
            int idx4 = tid * 2 + it;
            int r = idx4 >> 4, c4 = (idx4 & 15) * 4;
            float4 a = ld4(ag + (size_t)r * 512 + kc + c4);
            as_[r][c4+0]=a.x; as_[r][c4+1]=a.y; as_[r][c4+2]=a.z; as_[r][c4+3]=a.w;
        }
        #pragma unroll
        for (int it = 0; it < 4; ++it) {         // vp 64x64
            int idx4 = tid + it * 256;
            int r = idx4 >> 4, c4 = (idx4 & 15) * 4;
            float4 a = ld4(vg + (size_t)(kc + r) * 64 + c4);
            vs[r][c4+0]=a.x; vs[r][c4+1]=a.y; vs[r][c4+2]=a.z; vs[r][c4+3]=a.w;
        }
        __syncthreads();
        for (int kk = 0; kk < 64; ++kk) {
            float vv = vs[kk][d];
            #pragma unroll
            for (int u = 0; u < 8; ++u) acc[u] += as_[qb*8 + u][kk] * vv;
        }
    }
    #pragma unroll
    for (int u = 0; u < 8; ++u) {
        const int qg = q0 + qb*8 + u;
        pre[((size_t)(b*256 + qg) * 2 + i) * 512 + h*64 + d] = acc[u];
    }
}

// ---------------------------------------------------------------------------
// K7: residual + LayerNorm over D=512. One block per (b,q,i) row.
// ---------------------------------------------------------------------------
__global__ __launch_bounds__(256) void ln_k(
    const float* __restrict__ fcb, const float* __restrict__ qin,
    const float* __restrict__ lng, const float* __restrict__ lnb,
    float* __restrict__ out)
{
    __shared__ float red[8];
    const int row = blockIdx.x;
    const int tid = threadIdx.x;
    const float* fr = fcb + (size_t)row * 512;
    const float* qr = qin + (size_t)row * 512;
    float v0 = fr[tid]       + qr[tid];
    float v1 = fr[tid + 256] + qr[tid + 256];
    float s  = v0 + v1;
    float sq = v0*v0 + v1*v1;
    #pragma unroll
    for (int off = 32; off > 0; off >>= 1) {
        s  += __shfl_xor(s, off);
        sq += __shfl_xor(sq, off);
    }
    const int w = tid >> 6;
    if ((tid & 63) == 0) { red[w*2] = s; red[w*2 + 1] = sq; }
    __syncthreads();
    s  = red[0] + red[2] + red[4] + red[6];
    sq = red[1] + red[3] + red[5] + red[7];
    const float mu  = s * (1.f / 512.f);
    const float var = sq * (1.f / 512.f) - mu * mu;
    const float rs  = rsqrtf(var + 1e-6f);
    out[(size_t)row * 512 + tid]       = (v0 - mu) * rs * lng[tid]       + lnb[tid];
    out[(size_t)row * 512 + tid + 256] = (v1 - mu) * rs * lng[tid + 256] + lnb[tid + 256];
}

// ---------------------------------------------------------------------------
extern "C" void kernel_launch(void* const* d_in, const int* in_sizes, int n_in,
                              void* d_out, int out_size, void* d_ws, size_t ws_size,
                              hipStream_t stream) {
    (void)in_sizes; (void)n_in; (void)out_size; (void)ws_size;
    const float* qin    = (const float*)d_in[0];
    const float* kin    = (const float*)d_in[1];
    const float* vin    = (const float*)d_in[2];
    const int*   maskp  = (const int*)  d_in[3];
    const float* grm    = (const float*)d_in[4];
    const float* adj    = (const float*)d_in[5];
    const float* Wq     = (const float*)d_in[6];
    const float* Wk     = (const float*)d_in[7];
    const float* Wv     = (const float*)d_in[8];
    const float* Wq2    = (const float*)d_in[9];
    const float* Wk2    = (const float*)d_in[10];
    // d_in[11] = Wv2 (unused by the reference math)
    const float* Wfc    = (const float*)d_in[12];
    const float* grW1   = (const float*)d_in[13];
    const float* grb1   = (const float*)d_in[14];
    const float* grW2   = (const float*)d_in[15];
    const float* grb2   = (const float*)d_in[16];
    const float* lng    = (const float*)d_in[17];
    const float* lnb    = (const float*)d_in[18];
    float* out = (float*)d_out;

    float* ws = (float*)d_ws;
    const size_t M1 = 1048576;
    float* qp     = ws;
    float* qp2    = ws + 1*M1;
    float* kp     = ws + 2*M1;
    float* kp2    = ws + 3*M1;
    float* vp     = ws + 4*M1;
    float* pre    = ws + 5*M1;
    float* fcb    = ws + 6*M1;
    float* scores = ws + 7*M1;   // 8M floats

    // 1) projections: qp, qp2, kp, kp2, vp
    gemm_k<<<dim3(8, 16, 10), 256, 0, stream>>>(qin, kin, vin, Wq, Wk, Wv, Wq2, Wk2,
                                                pre, Wfc, qp, qp2, kp, kp2, vp, fcb, 0);
    // 2) gate MLP -> log_sigmoid staged into scores
    mlp_k<<<4096, 256, 0, stream>>>(grm, maskp, grW1, grb1, grW2, grb2, scores);
    // 3) scores (QK^T gate + staged lsig + mask)
    scores_k<<<dim3(8, 8, 128), 256, 0, stream>>>(qp, qp2, kp, kp2, adj, maskp, scores);
    // 4) softmax over (k,j)
    softmax_k<<<4096, 256, 0, stream>>>(scores);
    // 5) attn @ V -> pre
    pv_k<<<dim3(8, 64), 256, 0, stream>>>(scores, vp, pre);
    // 6) FC
    gemm_k<<<dim3(8, 16, 2), 256, 0, stream>>>(qin, kin, vin, Wq, Wk, Wv, Wq2, Wk2,
                                               pre, Wfc, qp, qp2, kp, kp2, vp, fcb, 10);
    // 7) residual + LayerNorm
    ln_k<<<2048, 256, 0, stream>>>(fcb, qin, lng, lnb, out);
}

// Round 3
// 585.627 us; speedup vs baseline: 1.7460x; 1.7460x over previous
//
#include <hip/hip_runtime.h>

// Problem constants: B=4, L=256, E=2 (both ensembles), D=512, H=8, dk=dv=64, KG=16.
// All fp32. Workspace layout (floats, 1M = 1048576):
//   qp:0  qp2:1M  kp:2M  kp2:3M  vp:4M  pre:5M  fcb:6M  scores:7M..15M
// Total ws requirement: 15*1048576*4 = 62.9 MB.

static __device__ __forceinline__ float4 ld4(const float* p) {
    return *reinterpret_cast<const float4*>(p);
}

// ---------------------------------------------------------------------------
// K1/K6: generic tiled GEMM, 64x64 tile, BK=16, 256 threads, 4x4 per thread.
// M=1024 rows (b*256+l), K=512, N=512. A row pointer = A + m*1024 + ens*512.
// mode 0: qp/kp-style output [ (b*2+ens)*8+h ][ l ][ d ]   (h=n>>6, d=n&63)
// mode 1: vp output          [ b*8+h ][ l*2+ens ][ d ]
// mode 2: fc output          [ (m*2+ens) ][ n ]
// ---------------------------------------------------------------------------
__global__ __launch_bounds__(256) void gemm_k(
    const float* __restrict__ qin, const float* __restrict__ kin, const float* __restrict__ vin,
    const float* __restrict__ Wq, const float* __restrict__ Wk, const float* __restrict__ Wv,
    const float* __restrict__ Wq2, const float* __restrict__ Wk2,
    const float* __restrict__ prebuf, const float* __restrict__ Wfc,
    float* __restrict__ qp, float* __restrict__ qp2, float* __restrict__ kp,
    float* __restrict__ kp2, float* __restrict__ vp, float* __restrict__ fcb,
    int mm_base)
{
    __shared__ float As[64][17];   // pad 17: conflict-free column reads
    __shared__ float Bs[16][64];   // float4-aligned rows

    const int mm = mm_base + (int)blockIdx.z;
    const float* A; const float* W; float* Cb; int ens; int mode;
    switch (mm) {
        case 0:  A=qin;    W=Wq;           Cb=qp;  ens=0; mode=0; break;
        case 1:  A=qin;    W=Wq + 262144;  Cb=qp;  ens=1; mode=0; break;
        case 2:  A=qin;    W=Wq2;          Cb=qp2; ens=0; mode=0; break;
        case 3:  A=qin;    W=Wq2 + 262144; Cb=qp2; ens=1; mode=0; break;
        case 4:  A=kin;    W=Wk;           Cb=kp;  ens=0; mode=0; break;
        case 5:  A=kin;    W=Wk + 262144;  Cb=kp;  ens=1; mode=0; break;
        case 6:  A=kin;    W=Wk2;          Cb=kp2; ens=0; mode=0; break;
        case 7:  A=kin;    W=Wk2 + 262144; Cb=kp2; ens=1; mode=0; break;
        case 8:  A=vin;    W=Wv;           Cb=vp;  ens=0; mode=1; break;
        case 9:  A=vin;    W=Wv + 262144;  Cb=vp;  ens=1; mode=1; break;
        case 10: A=prebuf; W=Wfc;          Cb=fcb; ens=0; mode=2; break;
        default: A=prebuf; W=Wfc + 262144; Cb=fcb; ens=1; mode=2; break;
    }

    const int tid = threadIdx.x;
    const int m0 = blockIdx.y * 64;
    const int n0 = blockIdx.x * 64;
    const int ty = tid >> 4, tx = tid & 15;
    const int ar = tid >> 2, ac = (tid & 3) * 4;   // A tile: 64 rows x 16 k
    const int br = tid >> 4, bc = (tid & 15) * 4;  // B tile: 16 k x 64 n

    float acc[4][4] = {};

    for (int kt = 0; kt < 512; kt += 16) {
        float4 av = ld4(A + (size_t)(m0 + ar) * 1024 + ens * 512 + kt + ac);
        float4 bv = ld4(W + (size_t)(kt + br) * 512 + n0 + bc);
        __syncthreads();
        As[ar][ac + 0] = av.x; As[ar][ac + 1] = av.y;
        As[ar][ac + 2] = av.z; As[ar][ac + 3] = av.w;
        *reinterpret_cast<float4*>(&Bs[br][bc]) = bv;
        __syncthreads();
        #pragma unroll
        for (int kk = 0; kk < 16; ++kk) {
            float a0 = As[ty*4+0][kk];
            float a1 = As[ty*4+1][kk];
            float a2 = As[ty*4+2][kk];
            float a3 = As[ty*4+3][kk];
            float4 b4 = *reinterpret_cast<const float4*>(&Bs[kk][tx*4]);
            acc[0][0] += a0*b4.x; acc[0][1] += a0*b4.y; acc[0][2] += a0*b4.z; acc[0][3] += a0*b4.w;
            acc[1][0] += a1*b4.x; acc[1][1] += a1*b4.y; acc[1][2] += a1*b4.z; acc[1][3] += a1*b4.w;
            acc[2][0] += a2*b4.x; acc[2][1] += a2*b4.y; acc[2][2] += a2*b4.z; acc[2][3] += a2*b4.w;
            acc[3][0] += a3*b4.x; acc[3][1] += a3*b4.y; acc[3][2] += a3*b4.z; acc[3][3] += a3*b4.w;
        }
    }

    #pragma unroll
    for (int u = 0; u < 4; ++u) {
        const int m = m0 + ty * 4 + u;
        const int b = m >> 8, l = m & 255;
        #pragma unroll
        for (int w = 0; w < 4; ++w) {
            const int n = n0 + tx * 4 + w;
            const int h = n >> 6, d = n & 63;
            size_t dst;
            if (mode == 0)      dst = ((size_t)((b*2 + ens)*8 + h) * 256 + l) * 64 + d;
            else if (mode == 1) dst = ((size_t)(b*8 + h) * 512 + l*2 + ens) * 64 + d;
            else                dst = ((size_t)m*2 + ens) * 512 + n;
            Cb[dst] = acc[u][w];
        }
    }
}

// ---------------------------------------------------------------------------
// K2: gate MLP. One block = 64 consecutive (b,q,l) rows (same b,q) x 32 combos.
// Thread (bl,c): bl=tid>>5 (8 row-groups), c=tid&31 (combo (i*2+j)*8+h).
// Register-blocked 4 rows/pass, 2 passes with "#pragma unroll 1" so only ONE
// tval[4][16] (64 VGPR) is live at a time (round-2 full unroll spilled).
// Writes log_sigmoid(agg) directly into scores[bih][q][k*2+j] (K3 does RMW add).
// ---------------------------------------------------------------------------
__global__ __launch_bounds__(256) void mlp_k(
    const float* __restrict__ gr_mask, const int* __restrict__ mask,
    const float* __restrict__ grW1, const float* __restrict__ grb1,
    const float* __restrict__ grW2, const float* __restrict__ grb2,
    float* __restrict__ scores)
{
    __shared__ float w1s[256][33];  // [(g*16+m)][c], pad 33 -> conflict-free over c
    __shared__ float b1s[16][33];   // [m][c]
    __shared__ float w2s[16][33];   // [m][c]
    __shared__ float b2s[32];
    __shared__ float ts[64][20];    // [row_local][g], pad 20 -> rows 16B-aligned
    __shared__ float ls[64][33];    // [row_local][c] staging for coalesced writeout

    const int tid = threadIdx.x;
    const int row_base = blockIdx.x * 64;
    const int b  = row_base >> 16;
    const int q  = (row_base >> 8) & 255;
    const int l0 = row_base & 255;

    #pragma unroll
    for (int it = 0; it < 32; ++it) {               // grW1: 8192 = c*256 + g*16 + m
        int flat = tid + it * 256;
        w1s[flat & 255][flat >> 8] = grW1[flat];
    }
    #pragma unroll
    for (int it = 0; it < 2; ++it) {                // grb1 / grW2: 512 = c*16 + m
        int flat = tid + it * 256;
        b1s[flat & 15][flat >> 4] = grb1[flat];
        w2s[flat & 15][flat >> 4] = grW2[flat];
    }
    if (tid < 32) b2s[tid] = grb2[tid];
    #pragma unroll
    for (int it = 0; it < 4; ++it) {                // t[b,q,l,g] = gr_mask[b,g,q,l]
        int flat = tid + it * 256;                  // 64 rows x 16 g
        int g = flat >> 6, r = flat & 63;
        ts[r][g] = gr_mask[(size_t)(b*16 + g) * 65536 + q * 256 + l0 + r];
    }
    __syncthreads();

    const int bl = tid >> 5, c = tid & 31;
    const float b2v = b2s[c];
    #pragma unroll 1
    for (int p = 0; p < 2; ++p) {
        float tval[4][16];
        #pragma unroll
        for (int u = 0; u < 4; ++u) {
            #pragma unroll
            for (int g4 = 0; g4 < 4; ++g4) {
                float4 tv = *reinterpret_cast<const float4*>(&ts[bl*8 + p*4 + u][g4*4]);
                tval[u][g4*4+0] = tv.x; tval[u][g4*4+1] = tv.y;
                tval[u][g4*4+2] = tv.z; tval[u][g4*4+3] = tv.w;
            }
        }

        float agg0 = b2v, agg1 = b2v, agg2 = b2v, agg3 = b2v;
        #pragma unroll
        for (int m = 0; m < 16; ++m) {
            float bb = b1s[m][c];
            float a0 = bb, a1 = bb, a2 = bb, a3 = bb;
            #pragma unroll
            for (int g = 0; g < 16; ++g) {
                float w = w1s[g*16 + m][c];
                a0 += tval[0][g] * w;
                a1 += tval[1][g] * w;
                a2 += tval[2][g] * w;
                a3 += tval[3][g] * w;
            }
            float w2 = w2s[m][c];
            agg0 += fmaxf(a0, 0.f) * w2;
            agg1 += fmaxf(a1, 0.f) * w2;
            agg2 += fmaxf(a2, 0.f) * w2;
            agg3 += fmaxf(a3, 0.f) * w2;
        }
        float aggs[4] = {agg0, agg1, agg2, agg3};
        #pragma unroll
        for (int u = 0; u < 4; ++u) {
            const int rl = bl*8 + p*4 + u;
            float agv = aggs[u];
            if (mask[(size_t)(b*256 + q) * 256 + l0 + rl] == 0) agv = 0.f;
            // stable log-sigmoid
            ls[rl][c] = fminf(agv, 0.f) - log1pf(expf(-fabsf(agv)));
        }
    }
    __syncthreads();

    // writeout: scores[(((b*2+i)*8+h)*256+q)*512 + k*2 + j], k = l0+r2, c2=(i*2+j)*8+h
    #pragma unroll
    for (int it = 0; it < 8; ++it) {
        int flat = tid + it * 256;      // 32 c x 64 r
        int c2 = flat >> 6, r2 = flat & 63;
        int ii = c2 >> 4, jj = (c2 >> 3) & 1, hh = c2 & 7;
        size_t dst = ((size_t)((b*2 + ii)*8 + hh) * 256 + q) * 512 + (size_t)(l0 + r2) * 2 + jj;
        scores[dst] = ls[r2][c2];
    }
}

// ---------------------------------------------------------------------------
// K3: scores. Block: fixed (b,i,h,j), 32x32 (q,k) tile. s1/s2 dots over d=64,
// gate with tril(adj), add the staged log-sigmoid (RMW), apply mask.
// ---------------------------------------------------------------------------
__global__ __launch_bounds__(256) void scores_k(
    const float* __restrict__ qp, const float* __restrict__ qp2,
    const float* __restrict__ kp, const float* __restrict__ kp2,
    const float* __restrict__ adj, const int* __restrict__ mask,
    float* __restrict__ scores)
{
    __shared__ float q1s[32][65], q2s[32][65], k1s[32][65], k2s[32][65];

    const int z = blockIdx.z;
    const int bih = z >> 1, j = z & 1;
    const int b = bih >> 4, i = (bih >> 3) & 1, h = bih & 7;
    const int bjh = (b*2 + j)*8 + h;
    const int q0 = blockIdx.y * 32, k0 = blockIdx.x * 32;
    const int tid = threadIdx.x;

    const float* q1g = qp  + (size_t)bih * 16384 + q0 * 64;
    const float* q2g = qp2 + (size_t)bih * 16384 + q0 * 64;
    const float* k1g = kp  + (size_t)bjh * 16384 + k0 * 64;
    const float* k2g = kp2 + (size_t)bjh * 16384 + k0 * 64;
    #pragma unroll
    for (int it = 0; it < 2; ++it) {
        int idx4 = tid * 2 + it;            // 512 float4 per tile
        int r = idx4 >> 4, c4 = (idx4 & 15) * 4;
        float4 a = ld4(q1g + r*64 + c4);
        float4 e = ld4(q2g + r*64 + c4);
        float4 f = ld4(k1g + r*64 + c4);
        float4 g = ld4(k2g + r*64 + c4);
        q1s[r][c4+0]=a.x; q1s[r][c4+1]=a.y; q1s[r][c4+2]=a.z; q1s[r][c4+3]=a.w;
        q2s[r][c4+0]=e.x; q2s[r][c4+1]=e.y; q2s[r][c4+2]=e.z; q2s[r][c4+3]=e.w;
        k1s[r][c4+0]=f.x; k1s[r][c4+1]=f.y; k1s[r][c4+2]=f.z; k1s[r][c4+3]=f.w;
        k2s[r][c4+0]=g.x; k2s[r][c4+1]=g.y; k2s[r][c4+2]=g.z; k2s[r][c4+3]=g.w;
    }
    __syncthreads();

    const int tk = tid & 31, tq = tid >> 5;   // tq 0..7, 4 q-rows per thread
    float acc1[4] = {}, acc2[4] = {};
    for (int dd = 0; dd < 64; ++dd) {
        float kv1 = k1s[tk][dd], kv2 = k2s[tk][dd];
        #pragma unroll
        for (int u = 0; u < 4; ++u) {
            acc1[u] += q1s[tq*4 + u][dd] * kv1;
            acc2[u] += q2s[tq*4 + u][dd] * kv2;
        }
    }

    const int kg = k0 + tk;
    #pragma unroll
    for (int u = 0; u < 4; ++u) {
        const int qg = q0 + tq*4 + u;
        const size_t mi = (size_t)(b*256 + qg) * 256 + kg;
        float gate = (qg >= kg) ? adj[mi] : 0.f;   // tril includes diagonal
        float s = (acc1[u] * gate + acc2[u] * (1.f - gate)) * 0.125f; // /sqrt(64)
        const size_t sidx = ((size_t)bih * 256 + qg) * 512 + (size_t)kg * 2 + j;
        s += scores[sidx];                          // staged log-sigmoid term
        if (mask[mi] == 0) s = -1e9f;
        scores[sidx] = s;
    }
}

// ---------------------------------------------------------------------------
// K4: softmax over 512 (k,j) per row. 4 waves/block, one row per wave.
// ---------------------------------------------------------------------------
__global__ __launch_bounds__(256) void softmax_k(float* __restrict__ scores)
{
    const int row  = blockIdx.x * 4 + (threadIdx.x >> 6);
    const int lane = threadIdx.x & 63;
    float* p = scores + (size_t)row * 512 + lane * 8;
    float4 v0 = *reinterpret_cast<float4*>(p);
    float4 v1 = *reinterpret_cast<float4*>(p + 4);
    float v[8] = {v0.x, v0.y, v0.z, v0.w, v1.x, v1.y, v1.z, v1.w};

    float m = v[0];
    #pragma unroll
    for (int t = 1; t < 8; ++t) m = fmaxf(m, v[t]);
    #pragma unroll
    for (int off = 32; off > 0; off >>= 1) m = fmaxf(m, __shfl_xor(m, off));

    float s = 0.f;
    #pragma unroll
    for (int t = 0; t < 8; ++t) { v[t] = expf(v[t] - m); s += v[t]; }
    #pragma unroll
    for (int off = 32; off > 0; off >>= 1) s += __shfl_xor(s, off);

    const float inv = 1.f / s;
    v0 = make_float4(v[0]*inv, v[1]*inv, v[2]*inv, v[3]*inv);
    v1 = make_float4(v[4]*inv, v[5]*inv, v[6]*inv, v[7]*inv);
    *reinterpret_cast<float4*>(p)     = v0;
    *reinterpret_cast<float4*>(p + 4) = v1;
}

// ---------------------------------------------------------------------------
// K5: PV. Block: fixed (b,i,h), 32 q-rows. attn[256x512] @ vp[512x64].
// ---------------------------------------------------------------------------
__global__ __launch_bounds__(256) void pv_k(
    const float* __restrict__ attn, const float* __restrict__ vp,
    float* __restrict__ pre)
{
    __shared__ float as_[32][65];
    __shared__ float vs[64][65];

    const int bih = blockIdx.y;
    const int b = bih >> 4, i = (bih >> 3) & 1, h = bih & 7;
    const int q0 = blockIdx.x * 32;
    const int tid = threadIdx.x;
    const int d = tid & 63, qb = tid >> 6;   // qb 0..3, 8 q-rows per thread

    const float* ag = attn + ((size_t)bih * 256 + q0) * 512;
    const float* vg = vp + (size_t)(b*8 + h) * 32768;

    float acc[8] = {};
    for (int kc = 0; kc < 512; kc += 64) {
        __syncthreads();
        #pragma unroll
        for (int it = 0; it < 2; ++it) {         // attn 32x64
            int idx4 = tid * 2 + it;
            int r = idx4 >> 4, c4 = (idx4 & 15) * 4;
            float4 a = ld4(ag + (size_t)r * 512 + kc + c4);
            as_[r][c4+0]=a.x; as_[r][c4+1]=a.y; as_[r][c4+2]=a.z; as_[r][c4+3]=a.w;
        }
        #pragma unroll
        for (int it = 0; it < 4; ++it) {         // vp 64x64
            int idx4 = tid + it * 256;
            int r = idx4 >> 4, c4 = (idx4 & 15) * 4;
            float4 a = ld4(vg + (size_t)(kc + r) * 64 + c4);
            vs[r][c4+0]=a.x; vs[r][c4+1]=a.y; vs[r][c4+2]=a.z; vs[r][c4+3]=a.w;
        }
        __syncthreads();
        for (int kk = 0; kk < 64; ++kk) {
            float vv = vs[kk][d];
            #pragma unroll
            for (int u = 0; u < 8; ++u) acc[u] += as_[qb*8 + u][kk] * vv;
        }
    }
    #pragma unroll
    for (int u = 0; u < 8; ++u) {
        const int qg = q0 + qb*8 + u;
        pre[((size_t)(b*256 + qg) * 2 + i) * 512 + h*64 + d] = acc[u];
    }
}

// ---------------------------------------------------------------------------
// K7: residual + LayerNorm over D=512. One block per (b,q,i) row.
// ---------------------------------------------------------------------------
__global__ __launch_bounds__(256) void ln_k(
    const float* __restrict__ fcb, const float* __restrict__ qin,
    const float* __restrict__ lng, const float* __restrict__ lnb,
    float* __restrict__ out)
{
    __shared__ float red[8];
    const int row = blockIdx.x;
    const int tid = threadIdx.x;
    const float* fr = fcb + (size_t)row * 512;
    const float* qr = qin + (size_t)row * 512;
    float v0 = fr[tid]       + qr[tid];
    float v1 = fr[tid + 256] + qr[tid + 256];
    float s  = v0 + v1;
    float sq = v0*v0 + v1*v1;
    #pragma unroll
    for (int off = 32; off > 0; off >>= 1) {
        s  += __shfl_xor(s, off);
        sq += __shfl_xor(sq, off);
    }
    const int w = tid >> 6;
    if ((tid & 63) == 0) { red[w*2] = s; red[w*2 + 1] = sq; }
    __syncthreads();
    s  = red[0] + red[2] + red[4] + red[6];
    sq = red[1] + red[3] + red[5] + red[7];
    const float mu  = s * (1.f / 512.f);
    const float var = sq * (1.f / 512.f) - mu * mu;
    const float rs  = rsqrtf(var + 1e-6f);
    out[(size_t)row * 512 + tid]       = (v0 - mu) * rs * lng[tid]       + lnb[tid];
    out[(size_t)row * 512 + tid + 256] = (v1 - mu) * rs * lng[tid + 256] + lnb[tid + 256];
}

// ---------------------------------------------------------------------------
extern "C" void kernel_launch(void* const* d_in, const int* in_sizes, int n_in,
                              void* d_out, int out_size, void* d_ws, size_t ws_size,
                              hipStream_t stream) {
    (void)in_sizes; (void)n_in; (void)out_size; (void)ws_size;
    const float* qin    = (const float*)d_in[0];
    const float* kin    = (const float*)d_in[1];
    const float* vin    = (const float*)d_in[2];
    const int*   maskp  = (const int*)  d_in[3];
    const float* grm    = (const float*)d_in[4];
    const float* adj    = (const float*)d_in[5];
    const float* Wq     = (const float*)d_in[6];
    const float* Wk     = (const float*)d_in[7];
    const float* Wv     = (const float*)d_in[8];
    const float* Wq2    = (const float*)d_in[9];
    const float* Wk2    = (const float*)d_in[10];
    // d_in[11] = Wv2 (unused by the reference math)
    const float* Wfc    = (const float*)d_in[12];
    const float* grW1   = (const float*)d_in[13];
    const float* grb1   = (const float*)d_in[14];
    const float* grW2   = (const float*)d_in[15];
    const float* grb2   = (const float*)d_in[16];
    const float* lng    = (const float*)d_in[17];
    const float* lnb    = (const float*)d_in[18];
    float* out = (float*)d_out;

    float* ws = (float*)d_ws;
    const size_t M1 = 1048576;
    float* qp     = ws;
    float* qp2    = ws + 1*M1;
    float* kp     = ws + 2*M1;
    float* kp2    = ws + 3*M1;
    float* vp     = ws + 4*M1;
    float* pre    = ws + 5*M1;
    float* fcb    = ws + 6*M1;
    float* scores = ws + 7*M1;   // 8M floats

    // 1) projections: qp, qp2, kp, kp2, vp
    gemm_k<<<dim3(8, 16, 10), 256, 0, stream>>>(qin, kin, vin, Wq, Wk, Wv, Wq2, Wk2,
                                                pre, Wfc, qp, qp2, kp, kp2, vp, fcb, 0);
    // 2) gate MLP -> log_sigmoid staged into scores
    mlp_k<<<4096, 256, 0, stream>>>(grm, maskp, grW1, grb1, grW2, grb2, scores);
    // 3) scores (QK^T gate + staged lsig + mask)
    scores_k<<<dim3(8, 8, 128), 256, 0, stream>>>(qp, qp2, kp, kp2, adj, maskp, scores);
    // 4) softmax over (k,j)
    softmax_k<<<4096, 256, 0, stream>>>(scores);
    // 5) attn @ V -> pre
    pv_k<<<dim3(8, 64), 256, 0, stream>>>(scores, vp, pre);
    // 6) FC
    gemm_k<<<dim3(8, 16, 2), 256, 0, stream>>>(qin, kin, vin, Wq, Wk, Wv, Wq2, Wk2,
                                               pre, Wfc, qp, qp2, kp, kp2, vp, fcb, 10);
    // 7) residual + LayerNorm
    ln_k<<<2048, 256, 0, stream>>>(fcb, qin, lng, lnb, out);
}

// Round 4
// 576.270 us; speedup vs baseline: 1.7743x; 1.0162x over previous
//
#include <hip/hip_runtime.h>

// Problem constants: B=4, L=256, E=2 (both ensembles), D=512, H=8, dk=dv=64, KG=16.
// All fp32. Workspace layout (floats, 1M = 1048576):
//   qp:0  qp2:1M  kp:2M  kp2:3M  vp:4M  pre:5M  fcb:6M  scores:7M..15M
// Total ws requirement: 15*1048576*4 = 62.9 MB.

static __device__ __forceinline__ float4 ld4(const float* p) {
    return *reinterpret_cast<const float4*>(p);
}

// ---------------------------------------------------------------------------
// K1/K6: generic tiled GEMM, 64x64 tile, BK=16, 256 threads, 4x4 per thread.
// ---------------------------------------------------------------------------
__global__ __launch_bounds__(256) void gemm_k(
    const float* __restrict__ qin, const float* __restrict__ kin, const float* __restrict__ vin,
    const float* __restrict__ Wq, const float* __restrict__ Wk, const float* __restrict__ Wv,
    const float* __restrict__ Wq2, const float* __restrict__ Wk2,
    const float* __restrict__ prebuf, const float* __restrict__ Wfc,
    float* __restrict__ qp, float* __restrict__ qp2, float* __restrict__ kp,
    float* __restrict__ kp2, float* __restrict__ vp, float* __restrict__ fcb,
    int mm_base)
{
    __shared__ float As[64][17];   // pad 17: conflict-free column reads
    __shared__ float Bs[16][64];   // float4-aligned rows

    const int mm = mm_base + (int)blockIdx.z;
    const float* A; const float* W; float* Cb; int ens; int mode;
    switch (mm) {
        case 0:  A=qin;    W=Wq;           Cb=qp;  ens=0; mode=0; break;
        case 1:  A=qin;    W=Wq + 262144;  Cb=qp;  ens=1; mode=0; break;
        case 2:  A=qin;    W=Wq2;          Cb=qp2; ens=0; mode=0; break;
        case 3:  A=qin;    W=Wq2 + 262144; Cb=qp2; ens=1; mode=0; break;
        case 4:  A=kin;    W=Wk;           Cb=kp;  ens=0; mode=0; break;
        case 5:  A=kin;    W=Wk + 262144;  Cb=kp;  ens=1; mode=0; break;
        case 6:  A=kin;    W=Wk2;          Cb=kp2; ens=0; mode=0; break;
        case 7:  A=kin;    W=Wk2 + 262144; Cb=kp2; ens=1; mode=0; break;
        case 8:  A=vin;    W=Wv;           Cb=vp;  ens=0; mode=1; break;
        case 9:  A=vin;    W=Wv + 262144;  Cb=vp;  ens=1; mode=1; break;
        case 10: A=prebuf; W=Wfc;          Cb=fcb; ens=0; mode=2; break;
        default: A=prebuf; W=Wfc + 262144; Cb=fcb; ens=1; mode=2; break;
    }

    const int tid = threadIdx.x;
    const int m0 = blockIdx.y * 64;
    const int n0 = blockIdx.x * 64;
    const int ty = tid >> 4, tx = tid & 15;
    const int ar = tid >> 2, ac = (tid & 3) * 4;   // A tile: 64 rows x 16 k
    const int br = tid >> 4, bc = (tid & 15) * 4;  // B tile: 16 k x 64 n

    float acc[4][4] = {};

    for (int kt = 0; kt < 512; kt += 16) {
        float4 av = ld4(A + (size_t)(m0 + ar) * 1024 + ens * 512 + kt + ac);
        float4 bv = ld4(W + (size_t)(kt + br) * 512 + n0 + bc);
        __syncthreads();
        As[ar][ac + 0] = av.x; As[ar][ac + 1] = av.y;
        As[ar][ac + 2] = av.z; As[ar][ac + 3] = av.w;
        *reinterpret_cast<float4*>(&Bs[br][bc]) = bv;
        __syncthreads();
        #pragma unroll
        for (int kk = 0; kk < 16; ++kk) {
            float a0 = As[ty*4+0][kk];
            float a1 = As[ty*4+1][kk];
            float a2 = As[ty*4+2][kk];
            float a3 = As[ty*4+3][kk];
            float4 b4 = *reinterpret_cast<const float4*>(&Bs[kk][tx*4]);
            acc[0][0] += a0*b4.x; acc[0][1] += a0*b4.y; acc[0][2] += a0*b4.z; acc[0][3] += a0*b4.w;
            acc[1][0] += a1*b4.x; acc[1][1] += a1*b4.y; acc[1][2] += a1*b4.z; acc[1][3] += a1*b4.w;
            acc[2][0] += a2*b4.x; acc[2][1] += a2*b4.y; acc[2][2] += a2*b4.z; acc[2][3] += a2*b4.w;
            acc[3][0] += a3*b4.x; acc[3][1] += a3*b4.y; acc[3][2] += a3*b4.z; acc[3][3] += a3*b4.w;
        }
    }

    #pragma unroll
    for (int u = 0; u < 4; ++u) {
        const int m = m0 + ty * 4 + u;
        const int b = m >> 8, l = m & 255;
        #pragma unroll
        for (int w = 0; w < 4; ++w) {
            const int n = n0 + tx * 4 + w;
            const int h = n >> 6, d = n & 63;
            size_t dst;
            if (mode == 0)      dst = ((size_t)((b*2 + ens)*8 + h) * 256 + l) * 64 + d;
            else if (mode == 1) dst = ((size_t)(b*8 + h) * 512 + l*2 + ens) * 64 + d;
            else                dst = ((size_t)m*2 + ens) * 512 + n;
            Cb[dst] = acc[u][w];
        }
    }
}

// ---------------------------------------------------------------------------
// K2: gate MLP, weights-in-registers structure.
// Block = 64 rows (fixed b,q). Thread = (c = tid>>3, rg = tid&7).
// Thread owns combo c for rows {rg, rg+8, ..., rg+56} (strided so the 8
// distinct t-row LDS addresses per wave hit disjoint bank spans).
// Two m-half passes (p=0,1), each holding w[8][16] (128 VGPR) of W1 in regs;
// agg[8] persists across passes (sum over m is separable through the ReLU).
// All LDS reads are ds_read_b128: weights broadcast 8-lanes/address,
// conflict-free (row stride 260 floats); t rows stride 20 floats.
// Writes log_sigmoid(agg) into scores[bih][q][k*2+j] (K3 does RMW add).
// ---------------------------------------------------------------------------
__global__ __launch_bounds__(256) void mlp_k(
    const float* __restrict__ gr_mask, const int* __restrict__ mask,
    const float* __restrict__ grW1, const float* __restrict__ grb1,
    const float* __restrict__ grW2, const float* __restrict__ grb2,
    float* __restrict__ scores)
{
    __shared__ float w1L[32][260];  // [c][m*16+g]; 1040B row stride: 16B-aligned,
                                    // 260%32=4 -> c=0..7 spans disjoint 4-bank groups
    __shared__ float b1s[16][33];   // [m][c]
    __shared__ float w2s[16][33];   // [m][c]
    __shared__ float b2s[32];
    __shared__ float ts[64][20];    // [row][g]; 80B stride: 16B-aligned, 20%32 -> 8 disjoint spans
    __shared__ float ls[64][36];    // [row][c]; stride 36 -> <=2-way on writes

    const int tid = threadIdx.x;
    const int row_base = blockIdx.x * 64;
    const int b  = row_base >> 16;
    const int q  = (row_base >> 8) & 255;
    const int l0 = row_base & 255;

    // stage w1: grW1 flat = c*256 + g*16 + m  ->  w1L[c][m*16+g]
    // (g fast in tid so LDS stores are conflict-free; global reads strided but
    //  only 32KB total, L2-hot after first iteration)
    #pragma unroll
    for (int it = 0; it < 32; ++it) {
        int flat = tid + it * 256;
        int c = flat >> 8, g = flat & 15, m = (flat >> 4) & 15;
        w1L[c][(m << 4) | g] = grW1[c * 256 + g * 16 + m];
    }
    #pragma unroll
    for (int it = 0; it < 2; ++it) {                // grb1 / grW2: 512 = c*16 + m
        int flat = tid + it * 256;
        b1s[flat & 15][flat >> 4] = grb1[flat];
        w2s[flat & 15][flat >> 4] = grW2[flat];
    }
    if (tid < 32) b2s[tid] = grb2[tid];
    #pragma unroll
    for (int it = 0; it < 4; ++it) {                // t[b,q,l,g] = gr_mask[b,g,q,l]
        int flat = tid + it * 256;                  // 64 rows x 16 g, r fast (coalesced)
        int g = flat >> 6, r = flat & 63;
        ts[r][g] = gr_mask[(size_t)(b*16 + g) * 65536 + q * 256 + l0 + r];
    }
    __syncthreads();

    const int c  = tid >> 3;   // 0..31
    const int rg = tid & 7;    // 0..7
    const float b2v = b2s[c];
    float agg[8];
    #pragma unroll
    for (int r = 0; r < 8; ++r) agg[r] = b2v;

    #pragma unroll 1
    for (int p = 0; p < 2; ++p) {
        // load this m-half's weights into registers (broadcast b128 reads)
        float w[8][16];
        #pragma unroll
        for (int m = 0; m < 8; ++m) {
            #pragma unroll
            for (int g4 = 0; g4 < 4; ++g4) {
                float4 wv = *reinterpret_cast<const float4*>(&w1L[c][(p*8 + m)*16 + g4*4]);
                w[m][g4*4+0] = wv.x; w[m][g4*4+1] = wv.y;
                w[m][g4*4+2] = wv.z; w[m][g4*4+3] = wv.w;
            }
        }
        float b1h[8], w2h[8];
        #pragma unroll
        for (int m = 0; m < 8; ++m) {
            b1h[m] = b1s[p*8 + m][c];
            w2h[m] = w2s[p*8 + m][c];
        }

        #pragma unroll
        for (int r = 0; r < 8; ++r) {
            const int row = rg + r*8;
            float t[16];
            #pragma unroll
            for (int g4 = 0; g4 < 4; ++g4) {
                float4 tv = *reinterpret_cast<const float4*>(&ts[row][g4*4]);
                t[g4*4+0] = tv.x; t[g4*4+1] = tv.y;
                t[g4*4+2] = tv.z; t[g4*4+3] = tv.w;
            }
            #pragma unroll
            for (int m = 0; m < 8; ++m) {
                float a = b1h[m];
                #pragma unroll
                for (int g = 0; g < 16; ++g) a += t[g] * w[m][g];
                agg[r] += fmaxf(a, 0.f) * w2h[m];
            }
        }
    }

    #pragma unroll
    for (int r = 0; r < 8; ++r) {
        const int row = rg + r*8;
        float agv = agg[r];
        if (mask[(size_t)(b*256 + q) * 256 + l0 + row] == 0) agv = 0.f;
        // stable log-sigmoid
        ls[row][c] = fminf(agv, 0.f) - log1pf(expf(-fabsf(agv)));
    }
    __syncthreads();

    // writeout: scores[(((b*2+i)*8+h)*256+q)*512 + k*2 + j], k = l0+r2, c2=(i*2+j)*8+h
    #pragma unroll
    for (int it = 0; it < 8; ++it) {
        int flat = tid + it * 256;      // 32 c x 64 r
        int c2 = flat >> 6, r2 = flat & 63;
        int ii = c2 >> 4, jj = (c2 >> 3) & 1, hh = c2 & 7;
        size_t dst = ((size_t)((b*2 + ii)*8 + hh) * 256 + q) * 512 + (size_t)(l0 + r2) * 2 + jj;
        scores[dst] = ls[r2][c2];
    }
}

// ---------------------------------------------------------------------------
// K3: scores. Block: fixed (b,i,h,j), 32x32 (q,k) tile. s1/s2 dots over d=64,
// gate with tril(adj), add the staged log-sigmoid (RMW), apply mask.
// ---------------------------------------------------------------------------
__global__ __launch_bounds__(256) void scores_k(
    const float* __restrict__ qp, const float* __restrict__ qp2,
    const float* __restrict__ kp, const float* __restrict__ kp2,
    const float* __restrict__ adj, const int* __restrict__ mask,
    float* __restrict__ scores)
{
    __shared__ float q1s[32][65], q2s[32][65], k1s[32][65], k2s[32][65];

    const int z = blockIdx.z;
    const int bih = z >> 1, j = z & 1;
    const int b = bih >> 4, i = (bih >> 3) & 1, h = bih & 7;
    const int bjh = (b*2 + j)*8 + h;
    const int q0 = blockIdx.y * 32, k0 = blockIdx.x * 32;
    const int tid = threadIdx.x;

    const float* q1g = qp  + (size_t)bih * 16384 + q0 * 64;
    const float* q2g = qp2 + (size_t)bih * 16384 + q0 * 64;
    const float* k1g = kp  + (size_t)bjh * 16384 + k0 * 64;
    const float* k2g = kp2 + (size_t)bjh * 16384 + k0 * 64;
    #pragma unroll
    for (int it = 0; it < 2; ++it) {
        int idx4 = tid * 2 + it;            // 512 float4 per tile
        int r = idx4 >> 4, c4 = (idx4 & 15) * 4;
        float4 a = ld4(q1g + r*64 + c4);
        float4 e = ld4(q2g + r*64 + c4);
        float4 f = ld4(k1g + r*64 + c4);
        float4 g = ld4(k2g + r*64 + c4);
        q1s[r][c4+0]=a.x; q1s[r][c4+1]=a.y; q1s[r][c4+2]=a.z; q1s[r][c4+3]=a.w;
        q2s[r][c4+0]=e.x; q2s[r][c4+1]=e.y; q2s[r][c4+2]=e.z; q2s[r][c4+3]=e.w;
        k1s[r][c4+0]=f.x; k1s[r][c4+1]=f.y; k1s[r][c4+2]=f.z; k1s[r][c4+3]=f.w;
        k2s[r][c4+0]=g.x; k2s[r][c4+1]=g.y; k2s[r][c4+2]=g.z; k2s[r][c4+3]=g.w;
    }
    __syncthreads();

    const int tk = tid & 31, tq = tid >> 5;   // tq 0..7, 4 q-rows per thread
    float acc1[4] = {}, acc2[4] = {};
    for (int dd = 0; dd < 64; ++dd) {
        float kv1 = k1s[tk][dd], kv2 = k2s[tk][dd];
        #pragma unroll
        for (int u = 0; u < 4; ++u) {
            acc1[u] += q1s[tq*4 + u][dd] * kv1;
            acc2[u] += q2s[tq*4 + u][dd] * kv2;
        }
    }

    const int kg = k0 + tk;
    #pragma unroll
    for (int u = 0; u < 4; ++u) {
        const int qg = q0 + tq*4 + u;
        const size_t mi = (size_t)(b*256 + qg) * 256 + kg;
        float gate = (qg >= kg) ? adj[mi] : 0.f;   // tril includes diagonal
        float s = (acc1[u] * gate + acc2[u] * (1.f - gate)) * 0.125f; // /sqrt(64)
        const size_t sidx = ((size_t)bih * 256 + qg) * 512 + (size_t)kg * 2 + j;
        s += scores[sidx];                          // staged log-sigmoid term
        if (mask[mi] == 0) s = -1e9f;
        scores[sidx] = s;
    }
}

// ---------------------------------------------------------------------------
// K4: softmax over 512 (k,j) per row. 4 waves/block, one row per wave.
// ---------------------------------------------------------------------------
__global__ __launch_bounds__(256) void softmax_k(float* __restrict__ scores)
{
    const int row  = blockIdx.x * 4 + (threadIdx.x >> 6);
    const int lane = threadIdx.x & 63;
    float* p = scores + (size_t)row * 512 + lane * 8;
    float4 v0 = *reinterpret_cast<float4*>(p);
    float4 v1 = *reinterpret_cast<float4*>(p + 4);
    float v[8] = {v0.x, v0.y, v0.z, v0.w, v1.x, v1.y, v1.z, v1.w};

    float m = v[0];
    #pragma unroll
    for (int t = 1; t < 8; ++t) m = fmaxf(m, v[t]);
    #pragma unroll
    for (int off = 32; off > 0; off >>= 1) m = fmaxf(m, __shfl_xor(m, off));

    float s = 0.f;
    #pragma unroll
    for (int t = 0; t < 8; ++t) { v[t] = expf(v[t] - m); s += v[t]; }
    #pragma unroll
    for (int off = 32; off > 0; off >>= 1) s += __shfl_xor(s, off);

    const float inv = 1.f / s;
    v0 = make_float4(v[0]*inv, v[1]*inv, v[2]*inv, v[3]*inv);
    v1 = make_float4(v[4]*inv, v[5]*inv, v[6]*inv, v[7]*inv);
    *reinterpret_cast<float4*>(p)     = v0;
    *reinterpret_cast<float4*>(p + 4) = v1;
}

// ---------------------------------------------------------------------------
// K5: PV. Block: fixed (b,i,h), 32 q-rows. attn[256x512] @ vp[512x64].
// ---------------------------------------------------------------------------
__global__ __launch_bounds__(256) void pv_k(
    const float* __restrict__ attn, const float* __restrict__ vp,
    float* __restrict__ pre)
{
    __shared__ float as_[32][65];
    __shared__ float vs[64][65];

    const int bih = blockIdx.y;
    const int b = bih >> 4, i = (bih >> 3) & 1, h = bih & 7;
    const int q0 = blockIdx.x * 32;
    const int tid = threadIdx.x;
    const int d = tid & 63, qb = tid >> 6;   // qb 0..3, 8 q-rows per thread

    const float* ag = attn + ((size_t)bih * 256 + q0) * 512;
    const float* vg = vp + (size_t)(b*8 + h) * 32768;

    float acc[8] = {};
    for (int kc = 0; kc < 512; kc += 64) {
        __syncthreads();
        #pragma unroll
        for (int it = 0; it < 2; ++it) {         // attn 32x64
            int idx4 = tid * 2 + it;
            int r = idx4 >> 4, c4 = (idx4 & 15) * 4;
            float4 a = ld4(ag + (size_t)r * 512 + kc + c4);
            as_[r][c4+0]=a.x; as_[r][c4+1]=a.y; as_[r][c4+2]=a.z; as_[r][c4+3]=a.w;
        }
        #pragma unroll
        for (int it = 0; it < 4; ++it) {         // vp 64x64
            int idx4 = tid + it * 256;
            int r = idx4 >> 4, c4 = (idx4 & 15) * 4;
            float4 a = ld4(vg + (size_t)(kc + r) * 64 + c4);
            vs[r][c4+0]=a.x; vs[r][c4+1]=a.y; vs[r][c4+2]=a.z; vs[r][c4+3]=a.w;
        }
        __syncthreads();
        for (int kk = 0; kk < 64; ++kk) {
            float vv = vs[kk][d];
            #pragma unroll
            for (int u = 0; u < 8; ++u) acc[u] += as_[qb*8 + u][kk] * vv;
        }
    }
    #pragma unroll
    for (int u = 0; u < 8; ++u) {
        const int qg = q0 + qb*8 + u;
        pre[((size_t)(b*256 + qg) * 2 + i) * 512 + h*64 + d] = acc[u];
    }
}

// ---------------------------------------------------------------------------
// K7: residual + LayerNorm over D=512. One block per (b,q,i) row.
// ---------------------------------------------------------------------------
__global__ __launch_bounds__(256) void ln_k(
    const float* __restrict__ fcb, const float* __restrict__ qin,
    const float* __restrict__ lng, const float* __restrict__ lnb,
    float* __restrict__ out)
{
    __shared__ float red[8];
    const int row = blockIdx.x;
    const int tid = threadIdx.x;
    const float* fr = fcb + (size_t)row * 512;
    const float* qr = qin + (size_t)row * 512;
    float v0 = fr[tid]       + qr[tid];
    float v1 = fr[tid + 256] + qr[tid + 256];
    float s  = v0 + v1;
    float sq = v0*v0 + v1*v1;
    #pragma unroll
    for (int off = 32; off > 0; off >>= 1) {
        s  += __shfl_xor(s, off);
        sq += __shfl_xor(sq, off);
    }
    const int w = tid >> 6;
    if ((tid & 63) == 0) { red[w*2] = s; red[w*2 + 1] = sq; }
    __syncthreads();
    s  = red[0] + red[2] + red[4] + red[6];
    sq = red[1] + red[3] + red[5] + red[7];
    const float mu  = s * (1.f / 512.f);
    const float var = sq * (1.f / 512.f) - mu * mu;
    const float rs  = rsqrtf(var + 1e-6f);
    out[(size_t)row * 512 + tid]       = (v0 - mu) * rs * lng[tid]       + lnb[tid];
    out[(size_t)row * 512 + tid + 256] = (v1 - mu) * rs * lng[tid + 256] + lnb[tid + 256];
}

// ---------------------------------------------------------------------------
extern "C" void kernel_launch(void* const* d_in, const int* in_sizes, int n_in,
                              void* d_out, int out_size, void* d_ws, size_t ws_size,
                              hipStream_t stream) {
    (void)in_sizes; (void)n_in; (void)out_size; (void)ws_size;
    const float* qin    = (const float*)d_in[0];
    const float* kin    = (const float*)d_in[1];
    const float* vin    = (const float*)d_in[2];
    const int*   maskp  = (const int*)  d_in[3];
    const float* grm    = (const float*)d_in[4];
    const float* adj    = (const float*)d_in[5];
    const float* Wq     = (const float*)d_in[6];
    const float* Wk     = (const float*)d_in[7];
    const float* Wv     = (const float*)d_in[8];
    const float* Wq2    = (const float*)d_in[9];
    const float* Wk2    = (const float*)d_in[10];
    // d_in[11] = Wv2 (unused by the reference math)
    const float* Wfc    = (const float*)d_in[12];
    const float* grW1   = (const float*)d_in[13];
    const float* grb1   = (const float*)d_in[14];
    const float* grW2   = (const float*)d_in[15];
    const float* grb2   = (const float*)d_in[16];
    const float* lng    = (const float*)d_in[17];
    const float* lnb    = (const float*)d_in[18];
    float* out = (float*)d_out;

    float* ws = (float*)d_ws;
    const size_t M1 = 1048576;
    float* qp     = ws;
    float* qp2    = ws + 1*M1;
    float* kp     = ws + 2*M1;
    float* kp2    = ws + 3*M1;
    float* vp     = ws + 4*M1;
    float* pre    = ws + 5*M1;
    float* fcb    = ws + 6*M1;
    float* scores = ws + 7*M1;   // 8M floats

    // 1) projections: qp, qp2, kp, kp2, vp
    gemm_k<<<dim3(8, 16, 10), 256, 0, stream>>>(qin, kin, vin, Wq, Wk, Wv, Wq2, Wk2,
                                                pre, Wfc, qp, qp2, kp, kp2, vp, fcb, 0);
    // 2) gate MLP -> log_sigmoid staged into scores
    mlp_k<<<4096, 256, 0, stream>>>(grm, maskp, grW1, grb1, grW2, grb2, scores);
    // 3) scores (QK^T gate + staged lsig + mask)
    scores_k<<<dim3(8, 8, 128), 256, 0, stream>>>(qp, qp2, kp, kp2, adj, maskp, scores);
    // 4) softmax over (k,j)
    softmax_k<<<4096, 256, 0, stream>>>(scores);
    // 5) attn @ V -> pre
    pv_k<<<dim3(8, 64), 256, 0, stream>>>(scores, vp, pre);
    // 6) FC
    gemm_k<<<dim3(8, 16, 2), 256, 0, stream>>>(qin, kin, vin, Wq, Wk, Wv, Wq2, Wk2,
                                               pre, Wfc, qp, qp2, kp, kp2, vp, fcb, 10);
    // 7) residual + LayerNorm
    ln_k<<<2048, 256, 0, stream>>>(fcb, qin, lng, lnb, out);
}

// Round 9
// 512.237 us; speedup vs baseline: 1.9961x; 1.1250x over previous
//
#include <hip/hip_runtime.h>

// B=4, L=256, E=2, D=512, H=8, dk=dv=64, KG=16.
// Workspace (byte offsets): scores f32 @0 (32MB) | attn_bf @32M (16MB) |
// pre f32 @48M (4MB) | qp_bf @52M | qp2_bf @54M | kp_bf @56M | kp2_bf @58M |
// vpT @60M (2MB each) | fcb f32 aliases @52M (qp_bf dead by then). Total 62MB.

typedef short  s16x8 __attribute__((ext_vector_type(8)));
typedef float  f32x4 __attribute__((ext_vector_type(4)));

static __device__ __forceinline__ float4 ld4(const float* p) {
    return *reinterpret_cast<const float4*>(p);
}
static __device__ __forceinline__ ushort f2bf(float f) {   // RNE f32->bf16
    unsigned u = __float_as_uint(f);
    return (ushort)((u + 0x7fffu + ((u >> 16) & 1u)) >> 16);
}

// ---------------------------------------------------------------------------
// K1/K6: fp32 tiled GEMM, 64x64 tile, BK=16. Projections now emit bf16.
// mode 0: qp/kp-style bf16 [bih][l][d]    mode 1: vpT bf16 [b8h][d][l*2+ens]
// mode 2: fc fp32 [(m*2+ens)][n]
// ---------------------------------------------------------------------------
__global__ __launch_bounds__(256) void gemm_k(
    const float* __restrict__ qin, const float* __restrict__ kin, const float* __restrict__ vin,
    const float* __restrict__ Wq, const float* __restrict__ Wk, const float* __restrict__ Wv,
    const float* __restrict__ Wq2, const float* __restrict__ Wk2,
    const float* __restrict__ prebuf, const float* __restrict__ Wfc,
    ushort* __restrict__ qp, ushort* __restrict__ qp2, ushort* __restrict__ kp,
    ushort* __restrict__ kp2, ushort* __restrict__ vpT, float* __restrict__ fcb,
    int mm_base)
{
    __shared__ float As[64][17];
    __shared__ float Bs[16][64];

    const int mm = mm_base + (int)blockIdx.z;
    const float* A; const float* W; ushort* Du = nullptr; int ens; int mode;
    switch (mm) {
        case 0:  A=qin;    W=Wq;           Du=qp;   ens=0; mode=0; break;
        case 1:  A=qin;    W=Wq + 262144;  Du=qp;   ens=1; mode=0; break;
        case 2:  A=qin;    W=Wq2;          Du=qp2;  ens=0; mode=0; break;
        case 3:  A=qin;    W=Wq2 + 262144; Du=qp2;  ens=1; mode=0; break;
        case 4:  A=kin;    W=Wk;           Du=kp;   ens=0; mode=0; break;
        case 5:  A=kin;    W=Wk + 262144;  Du=kp;   ens=1; mode=0; break;
        case 6:  A=kin;    W=Wk2;          Du=kp2;  ens=0; mode=0; break;
        case 7:  A=kin;    W=Wk2 + 262144; Du=kp2;  ens=1; mode=0; break;
        case 8:  A=vin;    W=Wv;           Du=vpT;  ens=0; mode=1; break;
        case 9:  A=vin;    W=Wv + 262144;  Du=vpT;  ens=1; mode=1; break;
        case 10: A=prebuf; W=Wfc;                   ens=0; mode=2; break;
        default: A=prebuf; W=Wfc + 262144;          ens=1; mode=2; break;
    }

    const int tid = threadIdx.x;
    const int m0 = blockIdx.y * 64;
    const int n0 = blockIdx.x * 64;
    const int ty = tid >> 4, tx = tid & 15;
    const int ar = tid >> 2, ac = (tid & 3) * 4;
    const int br = tid >> 4, bc = (tid & 15) * 4;

    float acc[4][4] = {};

    for (int kt = 0; kt < 512; kt += 16) {
        float4 av = ld4(A + (size_t)(m0 + ar) * 1024 + ens * 512 + kt + ac);
        float4 bv = ld4(W + (size_t)(kt + br) * 512 + n0 + bc);
        __syncthreads();
        As[ar][ac + 0] = av.x; As[ar][ac + 1] = av.y;
        As[ar][ac + 2] = av.z; As[ar][ac + 3] = av.w;
        *reinterpret_cast<float4*>(&Bs[br][bc]) = bv;
        __syncthreads();
        #pragma unroll
        for (int kk = 0; kk < 16; ++kk) {
            float a0 = As[ty*4+0][kk];
            float a1 = As[ty*4+1][kk];
            float a2 = As[ty*4+2][kk];
            float a3 = As[ty*4+3][kk];
            float4 b4 = *reinterpret_cast<const float4*>(&Bs[kk][tx*4]);
            acc[0][0] += a0*b4.x; acc[0][1] += a0*b4.y; acc[0][2] += a0*b4.z; acc[0][3] += a0*b4.w;
            acc[1][0] += a1*b4.x; acc[1][1] += a1*b4.y; acc[1][2] += a1*b4.z; acc[1][3] += a1*b4.w;
            acc[2][0] += a2*b4.x; acc[2][1] += a2*b4.y; acc[2][2] += a2*b4.z; acc[2][3] += a2*b4.w;
            acc[3][0] += a3*b4.x; acc[3][1] += a3*b4.y; acc[3][2] += a3*b4.z; acc[3][3] += a3*b4.w;
        }
    }

    const int hh = n0 >> 6;           // head: constant per block (64-col tiles)
    if (mode == 0) {
        #pragma unroll
        for (int u = 0; u < 4; ++u) {
            const int m = m0 + ty * 4 + u;
            const int bb = m >> 8, l = m & 255;
            ushort4 o;
            o.x = f2bf(acc[u][0]); o.y = f2bf(acc[u][1]);
            o.z = f2bf(acc[u][2]); o.w = f2bf(acc[u][3]);
            *reinterpret_cast<ushort4*>(
                Du + ((size_t)((bb*2 + ens)*8 + hh) * 256 + l) * 64 + tx*4) = o;
        }
    } else if (mode == 1) {
        #pragma unroll
        for (int u = 0; u < 4; ++u) {
            const int m = m0 + ty * 4 + u;
            const int bb = m >> 8, l = m & 255;
            #pragma unroll
            for (int w = 0; w < 4; ++w) {
                const int d = tx*4 + w;
                Du[(size_t)(bb*8 + hh) * 32768 + (size_t)d * 512 + l*2 + ens] =
                    f2bf(acc[u][w]);
            }
        }
    } else {
        #pragma unroll
        for (int u = 0; u < 4; ++u) {
            const int m = m0 + ty * 4 + u;
            #pragma unroll
            for (int w = 0; w < 4; ++w)
                fcb[((size_t)m*2 + ens) * 512 + n0 + tx*4 + w] = acc[u][w];
        }
    }
}

// ---------------------------------------------------------------------------
// K2: gate MLP (unchanged — control kernel).
// ---------------------------------------------------------------------------
__global__ __launch_bounds__(256) void mlp_k(
    const float* __restrict__ gr_mask, const int* __restrict__ mask,
    const float* __restrict__ grW1, const float* __restrict__ grb1,
    const float* __restrict__ grW2, const float* __restrict__ grb2,
    float* __restrict__ scores)
{
    __shared__ float w1L[32][260];
    __shared__ float b1s[16][33];
    __shared__ float w2s[16][33];
    __shared__ float b2s[32];
    __shared__ float ts[64][20];
    __shared__ float ls[64][36];

    const int tid = threadIdx.x;
    const int row_base = blockIdx.x * 64;
    const int b  = row_base >> 16;
    const int q  = (row_base >> 8) & 255;
    const int l0 = row_base & 255;

    #pragma unroll
    for (int it = 0; it < 32; ++it) {
        int flat = tid + it * 256;
        int c = flat >> 8, g = flat & 15, m = (flat >> 4) & 15;
        w1L[c][(m << 4) | g] = grW1[c * 256 + g * 16 + m];
    }
    #pragma unroll
    for (int it = 0; it < 2; ++it) {
        int flat = tid + it * 256;
        b1s[flat & 15][flat >> 4] = grb1[flat];
        w2s[flat & 15][flat >> 4] = grW2[flat];
    }
    if (tid < 32) b2s[tid] = grb2[tid];
    #pragma unroll
    for (int it = 0; it < 4; ++it) {
        int flat = tid + it * 256;
        int g = flat >> 6, r = flat & 63;
        ts[r][g] = gr_mask[(size_t)(b*16 + g) * 65536 + q * 256 + l0 + r];
    }
    __syncthreads();

    const int c  = tid >> 3;
    const int rg = tid & 7;
    const float b2v = b2s[c];
    float agg[8];
    #pragma unroll
    for (int r = 0; r < 8; ++r) agg[r] = b2v;

    #pragma unroll 1
    for (int p = 0; p < 2; ++p) {
        float w[8][16];
        #pragma unroll
        for (int m = 0; m < 8; ++m) {
            #pragma unroll
            for (int g4 = 0; g4 < 4; ++g4) {
                float4 wv = *reinterpret_cast<const float4*>(&w1L[c][(p*8 + m)*16 + g4*4]);
                w[m][g4*4+0] = wv.x; w[m][g4*4+1] = wv.y;
                w[m][g4*4+2] = wv.z; w[m][g4*4+3] = wv.w;
            }
        }
        float b1h[8], w2h[8];
        #pragma unroll
        for (int m = 0; m < 8; ++m) {
            b1h[m] = b1s[p*8 + m][c];
            w2h[m] = w2s[p*8 + m][c];
        }

        #pragma unroll
        for (int r = 0; r < 8; ++r) {
            const int row = rg + r*8;
            float t[16];
            #pragma unroll
            for (int g4 = 0; g4 < 4; ++g4) {
                float4 tv = *reinterpret_cast<const float4*>(&ts[row][g4*4]);
                t[g4*4+0] = tv.x; t[g4*4+1] = tv.y;
                t[g4*4+2] = tv.z; t[g4*4+3] = tv.w;
            }
            #pragma unroll
            for (int m = 0; m < 8; ++m) {
                float a = b1h[m];
                #pragma unroll
                for (int g = 0; g < 16; ++g) a += t[g] * w[m][g];
                agg[r] += fmaxf(a, 0.f) * w2h[m];
            }
        }
    }

    #pragma unroll
    for (int r = 0; r < 8; ++r) {
        const int row = rg + r*8;
        float agv = agg[r];
        if (mask[(size_t)(b*256 + q) * 256 + l0 + row] == 0) agv = 0.f;
        ls[row][c] = fminf(agv, 0.f) - log1pf(expf(-fabsf(agv)));
    }
    __syncthreads();

    #pragma unroll
    for (int it = 0; it < 8; ++it) {
        int flat = tid + it * 256;
        int c2 = flat >> 6, r2 = flat & 63;
        int ii = c2 >> 4, jj = (c2 >> 3) & 1, hh = c2 & 7;
        size_t dst = ((size_t)((b*2 + ii)*8 + hh) * 256 + q) * 512 + (size_t)(l0 + r2) * 2 + jj;
        scores[dst] = ls[r2][c2];
    }
}

// ---------------------------------------------------------------------------
// K3: scores via MFMA. Block: (q-half, k-half, bihj). 4 waves; wave owns 2
// q-tiles x 8 k-tiles. s = (mfma(q1,k1)*gate + mfma(q2,k2)*(1-gate))/8
//   + staged lsig (RMW), then mask. LDS tiles XOR-swizzled (T2).
// C layout (verified): col=lane&15 (k), row=(lane>>4)*4+reg (q).
// ---------------------------------------------------------------------------
__global__ __launch_bounds__(256) void scores_mfma(
    const ushort* __restrict__ qp, const ushort* __restrict__ qp2,
    const ushort* __restrict__ kp, const ushort* __restrict__ kp2,
    const float* __restrict__ adj, const int* __restrict__ mask,
    float* __restrict__ scores)
{
    __shared__ __align__(16) ushort q1t[128*64];
    __shared__ __align__(16) ushort q2t[128*64];
    __shared__ __align__(16) ushort k1t[128*64];
    __shared__ __align__(16) ushort k2t[128*64];

    const int z = blockIdx.z;
    const int bih = z >> 1, j = z & 1;
    const int b = bih >> 4, h = bih & 7;
    const int bjh = (b*2 + j)*8 + h;
    const int q0 = blockIdx.x * 128, k0 = blockIdx.y * 128;
    const int tid = threadIdx.x;

    const ushort* gq1 = qp  + (size_t)bih * 16384 + q0 * 64;
    const ushort* gq2 = qp2 + (size_t)bih * 16384 + q0 * 64;
    const ushort* gk1 = kp  + (size_t)bjh * 16384 + k0 * 64;
    const ushort* gk2 = kp2 + (size_t)bjh * 16384 + k0 * 64;
    #pragma unroll
    for (int it = 0; it < 4; ++it) {
        int ch = tid + it * 256;           // 1024 chunks of 8 ushort (16B)
        int row = ch >> 3, c8 = ch & 7;
        int byte = row * 128 + c8 * 16; byte ^= (row & 7) << 4;
        *reinterpret_cast<uint4*>((char*)q1t + byte) = *reinterpret_cast<const uint4*>(gq1 + ch*8);
        *reinterpret_cast<uint4*>((char*)q2t + byte) = *reinterpret_cast<const uint4*>(gq2 + ch*8);
        *reinterpret_cast<uint4*>((char*)k1t + byte) = *reinterpret_cast<const uint4*>(gk1 + ch*8);
        *reinterpret_cast<uint4*>((char*)k2t + byte) = *reinterpret_cast<const uint4*>(gk2 + ch*8);
    }
    __syncthreads();

    const int wv = tid >> 6, lane = tid & 63;
    const int lr = lane & 15, kg = lane >> 4;

    #pragma unroll 1
    for (int qi = 0; qi < 2; ++qi) {
        const int qt = wv * 2 + qi;
        s16x8 a1[2], a2[2];
        #pragma unroll
        for (int ks = 0; ks < 2; ++ks) {
            int row = qt*16 + lr;
            int byte = row*128 + (ks*32 + kg*8)*2; byte ^= (row & 7) << 4;
            a1[ks] = *reinterpret_cast<const s16x8*>((const char*)q1t + byte);
            a2[ks] = *reinterpret_cast<const s16x8*>((const char*)q2t + byte);
        }
        #pragma unroll 1
        for (int kt = 0; kt < 8; ++kt) {
            f32x4 acc1 = {0.f, 0.f, 0.f, 0.f};
            f32x4 acc2 = {0.f, 0.f, 0.f, 0.f};
            #pragma unroll
            for (int ks = 0; ks < 2; ++ks) {
                int row = kt*16 + lr;
                int byte = row*128 + (ks*32 + kg*8)*2; byte ^= (row & 7) << 4;
                s16x8 b1 = *reinterpret_cast<const s16x8*>((const char*)k1t + byte);
                s16x8 b2 = *reinterpret_cast<const s16x8*>((const char*)k2t + byte);
                acc1 = __builtin_amdgcn_mfma_f32_16x16x32_bf16(a1[ks], b1, acc1, 0, 0, 0);
                acc2 = __builtin_amdgcn_mfma_f32_16x16x32_bf16(a2[ks], b2, acc2, 0, 0, 0);
            }
            const int kgl = k0 + kt*16 + lr;
            #pragma unroll
            for (int r = 0; r < 4; ++r) {
                const int qg = q0 + qt*16 + kg*4 + r;
                const size_t mi = (size_t)(b*256 + qg) * 256 + kgl;
                float gate = (qg >= kgl) ? adj[mi] : 0.f;
                float s = (acc1[r]*gate + acc2[r]*(1.f - gate)) * 0.125f;
                const size_t sidx = ((size_t)bih * 256 + qg) * 512 + (size_t)kgl * 2 + j;
                s += scores[sidx];
                if (mask[mi] == 0) s = -1e9f;
                scores[sidx] = s;
            }
        }
    }
}

// ---------------------------------------------------------------------------
// K4: softmax over 512 per row; also emits bf16 attn copy for MFMA PV.
// ---------------------------------------------------------------------------
__global__ __launch_bounds__(256) void softmax_k(float* __restrict__ scores,
                                                 ushort* __restrict__ attn_bf)
{
    const int row  = blockIdx.x * 4 + (threadIdx.x >> 6);
    const int lane = threadIdx.x & 63;
    float* p = scores + (size_t)row * 512 + lane * 8;
    float4 v0 = *reinterpret_cast<float4*>(p);
    float4 v1 = *reinterpret_cast<float4*>(p + 4);
    float v[8] = {v0.x, v0.y, v0.z, v0.w, v1.x, v1.y, v1.z, v1.w};

    float m = v[0];
    #pragma unroll
    for (int t = 1; t < 8; ++t) m = fmaxf(m, v[t]);
    #pragma unroll
    for (int off = 32; off > 0; off >>= 1) m = fmaxf(m, __shfl_xor(m, off));

    float s = 0.f;
    #pragma unroll
    for (int t = 0; t < 8; ++t) { v[t] = expf(v[t] - m); s += v[t]; }
    #pragma unroll
    for (int off = 32; off > 0; off >>= 1) s += __shfl_xor(s, off);

    const float inv = 1.f / s;
    #pragma unroll
    for (int t = 0; t < 8; ++t) v[t] *= inv;
    *reinterpret_cast<float4*>(p)     = make_float4(v[0], v[1], v[2], v[3]);
    *reinterpret_cast<float4*>(p + 4) = make_float4(v[4], v[5], v[6], v[7]);

    ushort* pb = attn_bf + (size_t)row * 512 + lane * 8;
    ushort4 lo, hi;
    lo.x = f2bf(v[0]); lo.y = f2bf(v[1]); lo.z = f2bf(v[2]); lo.w = f2bf(v[3]);
    hi.x = f2bf(v[4]); hi.y = f2bf(v[5]); hi.z = f2bf(v[6]); hi.w = f2bf(v[7]);
    *reinterpret_cast<ushort4*>(pb)     = lo;
    *reinterpret_cast<ushort4*>(pb + 4) = hi;
}

// ---------------------------------------------------------------------------
// K5: PV via MFMA. Block: (q-quarter, bih). attn[64q x 512ke] @ vpT^T -> 64x64.
// K streamed in 4 chunks of 128; wave = 1 q-tile x 4 d-tiles, acc persists.
// ---------------------------------------------------------------------------
__global__ __launch_bounds__(256) void pv_mfma(
    const ushort* __restrict__ attn, const ushort* __restrict__ vpT,
    float* __restrict__ pre)
{
    __shared__ __align__(16) ushort at_t[64*128];
    __shared__ __align__(16) ushort v_t[64*128];

    const int bih = blockIdx.y;
    const int b = bih >> 4, i = (bih >> 3) & 1, h = bih & 7;
    const int q0 = blockIdx.x * 64;
    const int tid = threadIdx.x;
    const int wv = tid >> 6, lane = tid & 63;
    const int lr = lane & 15, kg = lane >> 4;

    const ushort* ga = attn + ((size_t)bih * 256 + q0) * 512;
    const ushort* gv = vpT + (size_t)(b*8 + h) * 32768;

    f32x4 acc[4];
    #pragma unroll
    for (int dt = 0; dt < 4; ++dt) acc[dt] = (f32x4){0.f, 0.f, 0.f, 0.f};

    #pragma unroll 1
    for (int kc = 0; kc < 4; ++kc) {
        __syncthreads();
        #pragma unroll
        for (int it = 0; it < 4; ++it) {
            int ch = tid + it * 256;       // 1024 chunks: row=ch>>4, c8=ch&15
            int row = ch >> 4, c8 = ch & 15;
            int byte = row * 256 + c8 * 16; byte ^= (row & 7) << 4;
            *reinterpret_cast<uint4*>((char*)at_t + byte) =
                *reinterpret_cast<const uint4*>(ga + (size_t)row*512 + kc*128 + c8*8);
            *reinterpret_cast<uint4*>((char*)v_t + byte) =
                *reinterpret_cast<const uint4*>(gv + (size_t)row*512 + kc*128 + c8*8);
        }
        __syncthreads();
        #pragma unroll
        for (int ks = 0; ks < 4; ++ks) {
            int arow = wv*16 + lr;
            int abyte = arow*256 + (ks*32 + kg*8)*2; abyte ^= (arow & 7) << 4;
            s16x8 a = *reinterpret_cast<const s16x8*>((const char*)at_t + abyte);
            #pragma unroll
            for (int dt = 0; dt < 4; ++dt) {
                int vrow = dt*16 + lr;
                int vbyte = vrow*256 + (ks*32 + kg*8)*2; vbyte ^= (vrow & 7) << 4;
                s16x8 bv = *reinterpret_cast<const s16x8*>((const char*)v_t + vbyte);
                acc[dt] = __builtin_amdgcn_mfma_f32_16x16x32_bf16(a, bv, acc[dt], 0, 0, 0);
            }
        }
    }

    #pragma unroll
    for (int dt = 0; dt < 4; ++dt) {
        const int d = dt*16 + lr;
        #pragma unroll
        for (int r = 0; r < 4; ++r) {
            const int qg = q0 + wv*16 + kg*4 + r;
            pre[((size_t)(b*256 + qg)*2 + i) * 512 + h*64 + d] = acc[dt][r];
        }
    }
}

// ---------------------------------------------------------------------------
// K7: residual + LayerNorm over D=512. One block per (b,q,i) row.
// ---------------------------------------------------------------------------
__global__ __launch_bounds__(256) void ln_k(
    const float* __restrict__ fcb, const float* __restrict__ qin,
    const float* __restrict__ lng, const float* __restrict__ lnb,
    float* __restrict__ out)
{
    __shared__ float red[8];
    const int row = blockIdx.x;
    const int tid = threadIdx.x;
    const float* fr = fcb + (size_t)row * 512;
    const float* qr = qin + (size_t)row * 512;
    float v0 = fr[tid]       + qr[tid];
    float v1 = fr[tid + 256] + qr[tid + 256];
    float s  = v0 + v1;
    float sq = v0*v0 + v1*v1;
    #pragma unroll
    for (int off = 32; off > 0; off >>= 1) {
        s  += __shfl_xor(s, off);
        sq += __shfl_xor(sq, off);
    }
    const int w = tid >> 6;
    if ((tid & 63) == 0) { red[w*2] = s; red[w*2 + 1] = sq; }
    __syncthreads();
    s  = red[0] + red[2] + red[4] + red[6];
    sq = red[1] + red[3] + red[5] + red[7];
    const float mu  = s * (1.f / 512.f);
    const float var = sq * (1.f / 512.f) - mu * mu;
    const float rs  = rsqrtf(var + 1e-6f);
    out[(size_t)row * 512 + tid]       = (v0 - mu) * rs * lng[tid]       + lnb[tid];
    out[(size_t)row * 512 + tid + 256] = (v1 - mu) * rs * lng[tid + 256] + lnb[tid + 256];
}

// ---------------------------------------------------------------------------
extern "C" void kernel_launch(void* const* d_in, const int* in_sizes, int n_in,
                              void* d_out, int out_size, void* d_ws, size_t ws_size,
                              hipStream_t stream) {
    (void)in_sizes; (void)n_in; (void)out_size; (void)ws_size;
    const float* qin    = (const float*)d_in[0];
    const float* kin    = (const float*)d_in[1];
    const float* vin    = (const float*)d_in[2];
    const int*   maskp  = (const int*)  d_in[3];
    const float* grm    = (const float*)d_in[4];
    const float* adj    = (const float*)d_in[5];
    const float* Wq     = (const float*)d_in[6];
    const float* Wk     = (const float*)d_in[7];
    const float* Wv     = (const float*)d_in[8];
    const float* Wq2    = (const float*)d_in[9];
    const float* Wk2    = (const float*)d_in[10];
    const float* Wfc    = (const float*)d_in[12];
    const float* grW1   = (const float*)d_in[13];
    const float* grb1   = (const float*)d_in[14];
    const float* grW2   = (const float*)d_in[15];
    const float* grb2   = (const float*)d_in[16];
    const float* lng    = (const float*)d_in[17];
    const float* lnb    = (const float*)d_in[18];
    float* out = (float*)d_out;

    char* w = (char*)d_ws;
    const size_t MB = 1048576;
    float*  scores  = (float*)(w);
    ushort* attn_bf = (ushort*)(w + 32*MB);
    float*  pre     = (float*) (w + 48*MB);
    ushort* qp_bf   = (ushort*)(w + 52*MB);
    ushort* qp2_bf  = (ushort*)(w + 54*MB);
    ushort* kp_bf   = (ushort*)(w + 56*MB);
    ushort* kp2_bf  = (ushort*)(w + 58*MB);
    ushort* vpT     = (ushort*)(w + 60*MB);
    float*  fcb     = (float*) (w + 52*MB);   // alias: qp_bf/qp2_bf dead by FC

    // 1) projections -> bf16 (qp/qp2/kp/kp2 [bih][l][d]; vpT [b8h][d][ke])
    gemm_k<<<dim3(8, 16, 10), 256, 0, stream>>>(qin, kin, vin, Wq, Wk, Wv, Wq2, Wk2,
                                                pre, Wfc, qp_bf, qp2_bf, kp_bf, kp2_bf,
                                                vpT, fcb, 0);
    // 2) gate MLP -> log_sigmoid staged into scores
    mlp_k<<<4096, 256, 0, stream>>>(grm, maskp, grW1, grb1, grW2, grb2, scores);
    // 3) scores via MFMA (QK^T gate + staged lsig + mask)
    scores_mfma<<<dim3(2, 2, 128), 256, 0, stream>>>(qp_bf, qp2_bf, kp_bf, kp2_bf,
                                                     adj, maskp, scores);
    // 4) softmax (+ bf16 attn copy)
    softmax_k<<<4096, 256, 0, stream>>>(scores, attn_bf);
    // 5) attn @ V via MFMA -> pre (fp32)
    pv_mfma<<<dim3(4, 64), 256, 0, stream>>>(attn_bf, vpT, pre);
    // 6) FC (fp32)
    gemm_k<<<dim3(8, 16, 2), 256, 0, stream>>>(qin, kin, vin, Wq, Wk, Wv, Wq2, Wk2,
                                               pre, Wfc, qp_bf, qp2_bf, kp_bf, kp2_bf,
                                               vpT, fcb, 10);
    // 7) residual + LayerNorm
    ln_k<<<2048, 256, 0, stream>>>(fcb, qin, lng, lnb, out);
}

// Round 10
// 373.451 us; speedup vs baseline: 2.7379x; 1.3716x over previous
//
#include <hip/hip_runtime.h>

// B=4, L=256, E=2, D=512, H=8, dk=dv=64, KG=16.
// Workspace (byte offsets): scores f32 @0 (32MB) | attn_bf @32M (16MB) |
// pre f32 @48M (4MB) | qp_bf @52M | qp2_bf @54M | kp_bf @56M | kp2_bf @58M |
// vpT @60M (2MB each) | fcb f32 aliases @52M (qp_bf dead by then). Total 62MB.

typedef short  s16x8 __attribute__((ext_vector_type(8)));
typedef float  f32x4 __attribute__((ext_vector_type(4)));

static __device__ __forceinline__ float4 ld4(const float* p) {
    return *reinterpret_cast<const float4*>(p);
}
static __device__ __forceinline__ ushort f2bf(float f) {   // RNE f32->bf16
    unsigned u = __float_as_uint(f);
    return (ushort)((u + 0x7fffu + ((u >> 16) & 1u)) >> 16);
}
static __device__ __forceinline__ float bf2f(ushort u) {
    return __uint_as_float((unsigned)u << 16);
}

// ---------------------------------------------------------------------------
// K1/K6: fp32 tiled GEMM, 64x64 tile, BK=16. Projections emit bf16.
// mode 0: qp/kp-style bf16 [bih][l][d]    mode 1: vpT bf16 [b8h][d][l*2+ens]
// mode 2: fc fp32 [(m*2+ens)][n]
// ---------------------------------------------------------------------------
__global__ __launch_bounds__(256) void gemm_k(
    const float* __restrict__ qin, const float* __restrict__ kin, const float* __restrict__ vin,
    const float* __restrict__ Wq, const float* __restrict__ Wk, const float* __restrict__ Wv,
    const float* __restrict__ Wq2, const float* __restrict__ Wk2,
    const float* __restrict__ prebuf, const float* __restrict__ Wfc,
    ushort* __restrict__ qp, ushort* __restrict__ qp2, ushort* __restrict__ kp,
    ushort* __restrict__ kp2, ushort* __restrict__ vpT, float* __restrict__ fcb,
    int mm_base)
{
    __shared__ float As[64][17];
    __shared__ float Bs[16][64];

    const int mm = mm_base + (int)blockIdx.z;
    const float* A; const float* W; ushort* Du = nullptr; int ens; int mode;
    switch (mm) {
        case 0:  A=qin;    W=Wq;           Du=qp;   ens=0; mode=0; break;
        case 1:  A=qin;    W=Wq + 262144;  Du=qp;   ens=1; mode=0; break;
        case 2:  A=qin;    W=Wq2;          Du=qp2;  ens=0; mode=0; break;
        case 3:  A=qin;    W=Wq2 + 262144; Du=qp2;  ens=1; mode=0; break;
        case 4:  A=kin;    W=Wk;           Du=kp;   ens=0; mode=0; break;
        case 5:  A=kin;    W=Wk + 262144;  Du=kp;   ens=1; mode=0; break;
        case 6:  A=kin;    W=Wk2;          Du=kp2;  ens=0; mode=0; break;
        case 7:  A=kin;    W=Wk2 + 262144; Du=kp2;  ens=1; mode=0; break;
        case 8:  A=vin;    W=Wv;           Du=vpT;  ens=0; mode=1; break;
        case 9:  A=vin;    W=Wv + 262144;  Du=vpT;  ens=1; mode=1; break;
        case 10: A=prebuf; W=Wfc;                   ens=0; mode=2; break;
        default: A=prebuf; W=Wfc + 262144;          ens=1; mode=2; break;
    }

    const int tid = threadIdx.x;
    const int m0 = blockIdx.y * 64;
    const int n0 = blockIdx.x * 64;
    const int ty = tid >> 4, tx = tid & 15;
    const int ar = tid >> 2, ac = (tid & 3) * 4;
    const int br = tid >> 4, bc = (tid & 15) * 4;

    float acc[4][4] = {};

    for (int kt = 0; kt < 512; kt += 16) {
        float4 av = ld4(A + (size_t)(m0 + ar) * 1024 + ens * 512 + kt + ac);
        float4 bv = ld4(W + (size_t)(kt + br) * 512 + n0 + bc);
        __syncthreads();
        As[ar][ac + 0] = av.x; As[ar][ac + 1] = av.y;
        As[ar][ac + 2] = av.z; As[ar][ac + 3] = av.w;
        *reinterpret_cast<float4*>(&Bs[br][bc]) = bv;
        __syncthreads();
        #pragma unroll
        for (int kk = 0; kk < 16; ++kk) {
            float a0 = As[ty*4+0][kk];
            float a1 = As[ty*4+1][kk];
            float a2 = As[ty*4+2][kk];
            float a3 = As[ty*4+3][kk];
            float4 b4 = *reinterpret_cast<const float4*>(&Bs[kk][tx*4]);
            acc[0][0] += a0*b4.x; acc[0][1] += a0*b4.y; acc[0][2] += a0*b4.z; acc[0][3] += a0*b4.w;
            acc[1][0] += a1*b4.x; acc[1][1] += a1*b4.y; acc[1][2] += a1*b4.z; acc[1][3] += a1*b4.w;
            acc[2][0] += a2*b4.x; acc[2][1] += a2*b4.y; acc[2][2] += a2*b4.z; acc[2][3] += a2*b4.w;
            acc[3][0] += a3*b4.x; acc[3][1] += a3*b4.y; acc[3][2] += a3*b4.z; acc[3][3] += a3*b4.w;
        }
    }

    const int hh = n0 >> 6;
    if (mode == 0) {
        #pragma unroll
        for (int u = 0; u < 4; ++u) {
            const int m = m0 + ty * 4 + u;
            const int bb = m >> 8, l = m & 255;
            ushort4 o;
            o.x = f2bf(acc[u][0]); o.y = f2bf(acc[u][1]);
            o.z = f2bf(acc[u][2]); o.w = f2bf(acc[u][3]);
            *reinterpret_cast<ushort4*>(
                Du + ((size_t)((bb*2 + ens)*8 + hh) * 256 + l) * 64 + tx*4) = o;
        }
    } else if (mode == 1) {
        #pragma unroll
        for (int u = 0; u < 4; ++u) {
            const int m = m0 + ty * 4 + u;
            const int bb = m >> 8, l = m & 255;
            #pragma unroll
            for (int w = 0; w < 4; ++w) {
                const int d = tx*4 + w;
                Du[(size_t)(bb*8 + hh) * 32768 + (size_t)d * 512 + l*2 + ens] =
                    f2bf(acc[u][w]);
            }
        }
    } else {
        #pragma unroll
        for (int u = 0; u < 4; ++u) {
            const int m = m0 + ty * 4 + u;
            #pragma unroll
            for (int w = 0; w < 4; ++w)
                fcb[((size_t)m*2 + ens) * 512 + n0 + tx*4 + w] = acc[u][w];
        }
    }
}

// ---------------------------------------------------------------------------
// K2: gate MLP via MFMA. One block = one (b,q): 256 l-rows x 32 combos.
// Stage 1 per combo c: D[m,l] = W1c^T (A, m-rows x g) @ t (B, l-rows x g) + b1
// using mfma_f32_16x16x32_bf16 with g zero-padded 16->32 (zeros in BOTH LDS
// operands). C layout: col=lane&15 (=l), row=(lane>>4)*4+r (=m) -> the
// m-reduction is 4 lane-local FMAs + shfl_xor(16)+shfl_xor(32).
// Wave = 4 l-tiles x 32 c, t-fragments register-resident (16 VGPR).
// agg staged bf16 in ls; finish pass applies mask+log-sigmoid and writes
// scores[bih][q][l*2+j] (scores_mfma then RMW-adds QK on top).
// ---------------------------------------------------------------------------
__global__ __launch_bounds__(256) void mlp_mfma(
    const float* __restrict__ gr_mask, const int* __restrict__ mask,
    const float* __restrict__ grW1, const float* __restrict__ grb1,
    const float* __restrict__ grW2, const float* __restrict__ grb2,
    float* __restrict__ scores)
{
    __shared__ __align__(16) ushort ts[256][40];     // [l][g], g16..31 zeroed, 20KB
    __shared__ __align__(16) ushort w1b[32][16][32]; // [c][m][g], g16..31 zeroed, 32KB
    __shared__ __align__(16) float  b1s[32][16];     // 2KB
    __shared__ __align__(16) float  w2s[32][16];     // 2KB
    __shared__ float b2s[32];
    __shared__ ushort ls[256][33];                   // agg bf16, 16.9KB

    const int tid = threadIdx.x;
    const int bq = blockIdx.x;
    const int b = bq >> 8, q = bq & 255;

    // --- zero the padded-g regions (LDS is uninitialized garbage) ---
    unsigned* w1w = (unsigned*)&w1b[0][0][0];        // 8192 words
    #pragma unroll
    for (int it = 0; it < 32; ++it) w1w[tid + it*256] = 0;
    unsigned* tsw = (unsigned*)&ts[0][0];            // rows of 20 words; zero words 8..15
    #pragma unroll
    for (int it = 0; it < 8; ++it) {
        int flat = tid + it*256;                     // 2048 = 256 rows x 8 words
        tsw[(flat >> 3) * 20 + 8 + (flat & 7)] = 0;
    }
    __syncthreads();

    // --- stage t: ts[l][g] = bf16(gr_mask[b,g,q,l]), coalesced over l=tid ---
    #pragma unroll
    for (int g = 0; g < 16; ++g)
        ts[tid][g] = f2bf(gr_mask[(size_t)(b*16 + g) * 65536 + q*256 + tid]);
    // --- stage W1^T: w1b[c][m][g] = bf16(grW1[c*256 + g*16 + m]) ---
    #pragma unroll
    for (int it = 0; it < 32; ++it) {
        int flat = tid + it*256;                     // 8192
        int c = flat >> 8, m = (flat >> 4) & 15, g = flat & 15;
        w1b[c][m][g] = f2bf(grW1[c*256 + g*16 + m]);
    }
    #pragma unroll
    for (int it = 0; it < 2; ++it) {                 // grb1/grW2: flat = c*16+m
        int flat = tid + it*256;
        b1s[flat >> 4][flat & 15] = grb1[flat];
        w2s[flat >> 4][flat & 15] = grW2[flat];
    }
    if (tid < 32) b2s[tid] = grb2[tid];
    __syncthreads();

    const int wv = tid >> 6, lane = tid & 63;
    const int lr = lane & 15, mg = lane >> 4;

    // t B-fragments for this wave's 4 l-tiles (row = l, k-elems = g chunk)
    s16x8 tf[4];
    #pragma unroll
    for (int lt = 0; lt < 4; ++lt) {
        int l = (wv*4 + lt)*16 + lr;
        tf[lt] = *reinterpret_cast<const s16x8*>(&ts[l][mg*8]);
    }

    #pragma unroll 1
    for (int c = 0; c < 32; ++c) {
        s16x8 af  = *reinterpret_cast<const s16x8*>(&w1b[c][lr][mg*8]); // A: m-row=lr
        f32x4 b1v = *reinterpret_cast<const f32x4*>(&b1s[c][mg*4]);     // C seed: m=mg*4+r
        f32x4 w2v = *reinterpret_cast<const f32x4*>(&w2s[c][mg*4]);
        const float b2v = b2s[c];

        f32x4 acc[4];
        #pragma unroll
        for (int lt = 0; lt < 4; ++lt)
            acc[lt] = __builtin_amdgcn_mfma_f32_16x16x32_bf16(af, tf[lt], b1v, 0, 0, 0);

        #pragma unroll
        for (int lt = 0; lt < 4; ++lt) {
            float s = fmaxf(acc[lt][0], 0.f) * w2v[0];
            s = fmaf(fmaxf(acc[lt][1], 0.f), w2v[1], s);
            s = fmaf(fmaxf(acc[lt][2], 0.f), w2v[2], s);
            s = fmaf(fmaxf(acc[lt][3], 0.f), w2v[3], s);
            s += __shfl_xor(s, 16);                  // fold mg groups
            s += __shfl_xor(s, 32);
            if (lane < 16)
                ls[(wv*4 + lt)*16 + lane][c] = f2bf(s + b2v);
        }
    }
    __syncthreads();

    // --- finish: mask, stable log-sigmoid, write to scores[bih][q][l*2+j] ---
    const int mv = mask[(size_t)(b*256 + q)*256 + tid];
    #pragma unroll 1
    for (int c2 = 0; c2 < 32; ++c2) {
        float agv = bf2f(ls[tid][c2]);
        if (mv == 0) agv = 0.f;
        float lsig = fminf(agv, 0.f) - log1pf(expf(-fabsf(agv)));
        int ii = c2 >> 4, jj = (c2 >> 3) & 1, hh = c2 & 7;
        scores[((size_t)((b*2 + ii)*8 + hh)*256 + q)*512 + (size_t)tid*2 + jj] = lsig;
    }
}

// ---------------------------------------------------------------------------
// K3: scores via MFMA (unchanged, verified round 9).
// ---------------------------------------------------------------------------
__global__ __launch_bounds__(256) void scores_mfma(
    const ushort* __restrict__ qp, const ushort* __restrict__ qp2,
    const ushort* __restrict__ kp, const ushort* __restrict__ kp2,
    const float* __restrict__ adj, const int* __restrict__ mask,
    float* __restrict__ scores)
{
    __shared__ __align__(16) ushort q1t[128*64];
    __shared__ __align__(16) ushort q2t[128*64];
    __shared__ __align__(16) ushort k1t[128*64];
    __shared__ __align__(16) ushort k2t[128*64];

    const int z = blockIdx.z;
    const int bih = z >> 1, j = z & 1;
    const int b = bih >> 4, h = bih & 7;
    const int bjh = (b*2 + j)*8 + h;
    const int q0 = blockIdx.x * 128, k0 = blockIdx.y * 128;
    const int tid = threadIdx.x;

    const ushort* gq1 = qp  + (size_t)bih * 16384 + q0 * 64;
    const ushort* gq2 = qp2 + (size_t)bih * 16384 + q0 * 64;
    const ushort* gk1 = kp  + (size_t)bjh * 16384 + k0 * 64;
    const ushort* gk2 = kp2 + (size_t)bjh * 16384 + k0 * 64;
    #pragma unroll
    for (int it = 0; it < 4; ++it) {
        int ch = tid + it * 256;
        int row = ch >> 3, c8 = ch & 7;
        int byte = row * 128 + c8 * 16; byte ^= (row & 7) << 4;
        *reinterpret_cast<uint4*>((char*)q1t + byte) = *reinterpret_cast<const uint4*>(gq1 + ch*8);
        *reinterpret_cast<uint4*>((char*)q2t + byte) = *reinterpret_cast<const uint4*>(gq2 + ch*8);
        *reinterpret_cast<uint4*>((char*)k1t + byte) = *reinterpret_cast<const uint4*>(gk1 + ch*8);
        *reinterpret_cast<uint4*>((char*)k2t + byte) = *reinterpret_cast<const uint4*>(gk2 + ch*8);
    }
    __syncthreads();

    const int wv = tid >> 6, lane = tid & 63;
    const int lr = lane & 15, kg = lane >> 4;

    #pragma unroll 1
    for (int qi = 0; qi < 2; ++qi) {
        const int qt = wv * 2 + qi;
        s16x8 a1[2], a2[2];
        #pragma unroll
        for (int ks = 0; ks < 2; ++ks) {
            int row = qt*16 + lr;
            int byte = row*128 + (ks*32 + kg*8)*2; byte ^= (row & 7) << 4;
            a1[ks] = *reinterpret_cast<const s16x8*>((const char*)q1t + byte);
            a2[ks] = *reinterpret_cast<const s16x8*>((const char*)q2t + byte);
        }
        #pragma unroll 1
        for (int kt = 0; kt < 8; ++kt) {
            f32x4 acc1 = {0.f, 0.f, 0.f, 0.f};
            f32x4 acc2 = {0.f, 0.f, 0.f, 0.f};
            #pragma unroll
            for (int ks = 0; ks < 2; ++ks) {
                int row = kt*16 + lr;
                int byte = row*128 + (ks*32 + kg*8)*2; byte ^= (row & 7) << 4;
                s16x8 b1 = *reinterpret_cast<const s16x8*>((const char*)k1t + byte);
                s16x8 b2 = *reinterpret_cast<const s16x8*>((const char*)k2t + byte);
                acc1 = __builtin_amdgcn_mfma_f32_16x16x32_bf16(a1[ks], b1, acc1, 0, 0, 0);
                acc2 = __builtin_amdgcn_mfma_f32_16x16x32_bf16(a2[ks], b2, acc2, 0, 0, 0);
            }
            const int kgl = k0 + kt*16 + lr;
            #pragma unroll
            for (int r = 0; r < 4; ++r) {
                const int qg = q0 + qt*16 + kg*4 + r;
                const size_t mi = (size_t)(b*256 + qg) * 256 + kgl;
                float gate = (qg >= kgl) ? adj[mi] : 0.f;
                float s = (acc1[r]*gate + acc2[r]*(1.f - gate)) * 0.125f;
                const size_t sidx = ((size_t)bih * 256 + qg) * 512 + (size_t)kgl * 2 + j;
                s += scores[sidx];
                if (mask[mi] == 0) s = -1e9f;
                scores[sidx] = s;
            }
        }
    }
}

// ---------------------------------------------------------------------------
// K4: softmax over 512 per row; also emits bf16 attn copy for MFMA PV.
// ---------------------------------------------------------------------------
__global__ __launch_bounds__(256) void softmax_k(float* __restrict__ scores,
                                                 ushort* __restrict__ attn_bf)
{
    const int row  = blockIdx.x * 4 + (threadIdx.x >> 6);
    const int lane = threadIdx.x & 63;
    float* p = scores + (size_t)row * 512 + lane * 8;
    float4 v0 = *reinterpret_cast<float4*>(p);
    float4 v1 = *reinterpret_cast<float4*>(p + 4);
    float v[8] = {v0.x, v0.y, v0.z, v0.w, v1.x, v1.y, v1.z, v1.w};

    float m = v[0];
    #pragma unroll
    for (int t = 1; t < 8; ++t) m = fmaxf(m, v[t]);
    #pragma unroll
    for (int off = 32; off > 0; off >>= 1) m = fmaxf(m, __shfl_xor(m, off));

    float s = 0.f;
    #pragma unroll
    for (int t = 0; t < 8; ++t) { v[t] = expf(v[t] - m); s += v[t]; }
    #pragma unroll
    for (int off = 32; off > 0; off >>= 1) s += __shfl_xor(s, off);

    const float inv = 1.f / s;
    #pragma unroll
    for (int t = 0; t < 8; ++t) v[t] *= inv;
    *reinterpret_cast<float4*>(p)     = make_float4(v[0], v[1], v[2], v[3]);
    *reinterpret_cast<float4*>(p + 4) = make_float4(v[4], v[5], v[6], v[7]);

    ushort* pb = attn_bf + (size_t)row * 512 + lane * 8;
    ushort4 lo, hi;
    lo.x = f2bf(v[0]); lo.y = f2bf(v[1]); lo.z = f2bf(v[2]); lo.w = f2bf(v[3]);
    hi.x = f2bf(v[4]); hi.y = f2bf(v[5]); hi.z = f2bf(v[6]); hi.w = f2bf(v[7]);
    *reinterpret_cast<ushort4*>(pb)     = lo;
    *reinterpret_cast<ushort4*>(pb + 4) = hi;
}

// ---------------------------------------------------------------------------
// K5: PV via MFMA (unchanged, verified round 9).
// ---------------------------------------------------------------------------
__global__ __launch_bounds__(256) void pv_mfma(
    const ushort* __restrict__ attn, const ushort* __restrict__ vpT,
    float* __restrict__ pre)
{
    __shared__ __align__(16) ushort at_t[64*128];
    __shared__ __align__(16) ushort v_t[64*128];

    const int bih = blockIdx.y;
    const int b = bih >> 4, i = (bih >> 3) & 1, h = bih & 7;
    const int q0 = blockIdx.x * 64;
    const int tid = threadIdx.x;
    const int wv = tid >> 6, lane = tid & 63;
    const int lr = lane & 15, kg = lane >> 4;

    const ushort* ga = attn + ((size_t)bih * 256 + q0) * 512;
    const ushort* gv = vpT + (size_t)(b*8 + h) * 32768;

    f32x4 acc[4];
    #pragma unroll
    for (int dt = 0; dt < 4; ++dt) acc[dt] = (f32x4){0.f, 0.f, 0.f, 0.f};

    #pragma unroll 1
    for (int kc = 0; kc < 4; ++kc) {
        __syncthreads();
        #pragma unroll
        for (int it = 0; it < 4; ++it) {
            int ch = tid + it * 256;
            int row = ch >> 4, c8 = ch & 15;
            int byte = row * 256 + c8 * 16; byte ^= (row & 7) << 4;
            *reinterpret_cast<uint4*>((char*)at_t + byte) =
                *reinterpret_cast<const uint4*>(ga + (size_t)row*512 + kc*128 + c8*8);
            *reinterpret_cast<uint4*>((char*)v_t + byte) =
                *reinterpret_cast<const uint4*>(gv + (size_t)row*512 + kc*128 + c8*8);
        }
        __syncthreads();
        #pragma unroll
        for (int ks = 0; ks < 4; ++ks) {
            int arow = wv*16 + lr;
            int abyte = arow*256 + (ks*32 + kg*8)*2; abyte ^= (arow & 7) << 4;
            s16x8 a = *reinterpret_cast<const s16x8*>((const char*)at_t + abyte);
            #pragma unroll
            for (int dt = 0; dt < 4; ++dt) {
                int vrow = dt*16 + lr;
                int vbyte = vrow*256 + (ks*32 + kg*8)*2; vbyte ^= (vrow & 7) << 4;
                s16x8 bv = *reinterpret_cast<const s16x8*>((const char*)v_t + vbyte);
                acc[dt] = __builtin_amdgcn_mfma_f32_16x16x32_bf16(a, bv, acc[dt], 0, 0, 0);
            }
        }
    }

    #pragma unroll
    for (int dt = 0; dt < 4; ++dt) {
        const int d = dt*16 + lr;
        #pragma unroll
        for (int r = 0; r < 4; ++r) {
            const int qg = q0 + wv*16 + kg*4 + r;
            pre[((size_t)(b*256 + qg)*2 + i) * 512 + h*64 + d] = acc[dt][r];
        }
    }
}

// ---------------------------------------------------------------------------
// K7: residual + LayerNorm over D=512. One block per (b,q,i) row.
// ---------------------------------------------------------------------------
__global__ __launch_bounds__(256) void ln_k(
    const float* __restrict__ fcb, const float* __restrict__ qin,
    const float* __restrict__ lng, const float* __restrict__ lnb,
    float* __restrict__ out)
{
    __shared__ float red[8];
    const int row = blockIdx.x;
    const int tid = threadIdx.x;
    const float* fr = fcb + (size_t)row * 512;
    const float* qr = qin + (size_t)row * 512;
    float v0 = fr[tid]       + qr[tid];
    float v1 = fr[tid + 256] + qr[tid + 256];
    float s  = v0 + v1;
    float sq = v0*v0 + v1*v1;
    #pragma unroll
    for (int off = 32; off > 0; off >>= 1) {
        s  += __shfl_xor(s, off);
        sq += __shfl_xor(sq, off);
    }
    const int w = tid >> 6;
    if ((tid & 63) == 0) { red[w*2] = s; red[w*2 + 1] = sq; }
    __syncthreads();
    s  = red[0] + red[2] + red[4] + red[6];
    sq = red[1] + red[3] + red[5] + red[7];
    const float mu  = s * (1.f / 512.f);
    const float var = sq * (1.f / 512.f) - mu * mu;
    const float rs  = rsqrtf(var + 1e-6f);
    out[(size_t)row * 512 + tid]       = (v0 - mu) * rs * lng[tid]       + lnb[tid];
    out[(size_t)row * 512 + tid + 256] = (v1 - mu) * rs * lng[tid + 256] + lnb[tid + 256];
}

// ---------------------------------------------------------------------------
extern "C" void kernel_launch(void* const* d_in, const int* in_sizes, int n_in,
                              void* d_out, int out_size, void* d_ws, size_t ws_size,
                              hipStream_t stream) {
    (void)in_sizes; (void)n_in; (void)out_size; (void)ws_size;
    const float* qin    = (const float*)d_in[0];
    const float* kin    = (const float*)d_in[1];
    const float* vin    = (const float*)d_in[2];
    const int*   maskp  = (const int*)  d_in[3];
    const float* grm    = (const float*)d_in[4];
    const float* adj    = (const float*)d_in[5];
    const float* Wq     = (const float*)d_in[6];
    const float* Wk     = (const float*)d_in[7];
    const float* Wv     = (const float*)d_in[8];
    const float* Wq2    = (const float*)d_in[9];
    const float* Wk2    = (const float*)d_in[10];
    const float* Wfc    = (const float*)d_in[12];
    const float* grW1   = (const float*)d_in[13];
    const float* grb1   = (const float*)d_in[14];
    const float* grW2   = (const float*)d_in[15];
    const float* grb2   = (const float*)d_in[16];
    const float* lng    = (const float*)d_in[17];
    const float* lnb    = (const float*)d_in[18];
    float* out = (float*)d_out;

    char* w = (char*)d_ws;
    const size_t MB = 1048576;
    float*  scores  = (float*)(w);
    ushort* attn_bf = (ushort*)(w + 32*MB);
    float*  pre     = (float*) (w + 48*MB);
    ushort* qp_bf   = (ushort*)(w + 52*MB);
    ushort* qp2_bf  = (ushort*)(w + 54*MB);
    ushort* kp_bf   = (ushort*)(w + 56*MB);
    ushort* kp2_bf  = (ushort*)(w + 58*MB);
    ushort* vpT     = (ushort*)(w + 60*MB);
    float*  fcb     = (float*) (w + 52*MB);   // alias: qp_bf/qp2_bf dead by FC

    // 1) projections -> bf16 (qp/qp2/kp/kp2 [bih][l][d]; vpT [b8h][d][ke])
    gemm_k<<<dim3(8, 16, 10), 256, 0, stream>>>(qin, kin, vin, Wq, Wk, Wv, Wq2, Wk2,
                                                pre, Wfc, qp_bf, qp2_bf, kp_bf, kp2_bf,
                                                vpT, fcb, 0);
    // 2) gate MLP via MFMA -> log_sigmoid staged into scores
    mlp_mfma<<<1024, 256, 0, stream>>>(grm, maskp, grW1, grb1, grW2, grb2, scores);
    // 3) scores via MFMA (QK^T gate + staged lsig + mask)
    scores_mfma<<<dim3(2, 2, 128), 256, 0, stream>>>(qp_bf, qp2_bf, kp_bf, kp2_bf,
                                                     adj, maskp, scores);
    // 4) softmax (+ bf16 attn copy)
    softmax_k<<<4096, 256, 0, stream>>>(scores, attn_bf);
    // 5) attn @ V via MFMA -> pre (fp32)
    pv_mfma<<<dim3(4, 64), 256, 0, stream>>>(attn_bf, vpT, pre);
    // 6) FC (fp32)
    gemm_k<<<dim3(8, 16, 2), 256, 0, stream>>>(qin, kin, vin, Wq, Wk, Wv, Wq2, Wk2,
                                               pre, Wfc, qp_bf, qp2_bf, kp_bf, kp2_bf,
                                               vpT, fcb, 10);
    // 7) residual + LayerNorm
    ln_k<<<2048, 256, 0, stream>>>(fcb, qin, lng, lnb, out);
}

// Round 13
// 305.789 us; speedup vs baseline: 3.3438x; 1.2213x over previous
//
#include <hip/hip_runtime.h>

// B=4, L=256, E=2, D=512, H=8, dk=dv=64, KG=16.
// Workspace (byte offsets), 62MB total:
//   scores f32 @0 (32MB)
//   attn_bf @32M (16MB); WT bf16 aliases @32M (<=5.25MB) in attn_bf's dead
//     windows: proj weights (steps 0-1), Wfc (steps 5.5-6, attn_bf dead).
//   pre f32 @48M (4MB)
//   qp_bf @52M | qp2_bf @54M | kp_bf @56M | kp2_bf @58M | vpT @60M (2MB each)
//   fcb f32 aliases @52M (4MB; qp_bf/qp2_bf dead by FC)

typedef short  s16x8 __attribute__((ext_vector_type(8)));
typedef float  f32x4 __attribute__((ext_vector_type(4)));

static __device__ __forceinline__ float4 ld4(const float* p) {
    return *reinterpret_cast<const float4*>(p);
}
static __device__ __forceinline__ ushort f2bf(float f) {   // RNE f32->bf16
    unsigned u = __float_as_uint(f);
    return (ushort)((u + 0x7fffu + ((u >> 16) & 1u)) >> 16);
}
static __device__ __forceinline__ float bf2f(ushort u) {
    return __uint_as_float((unsigned)u << 16);
}

// ---------------------------------------------------------------------------
// K0: weight transpose+convert. WT[mat][n][k] = bf16(Wsrc[ens][k][n]).
// mat = base + z: 0..9 -> {Wq,Wq2,Wk,Wk2,Wv} x ens; 10..11 -> Wfc x ens.
// 64x64 LDS tile transpose, pad 65 (2-way max on column reads).
// ---------------------------------------------------------------------------
__global__ __launch_bounds__(256) void cvt_w(
    const float* __restrict__ Wq, const float* __restrict__ Wq2,
    const float* __restrict__ Wk, const float* __restrict__ Wk2,
    const float* __restrict__ Wv, const float* __restrict__ Wfc,
    ushort* __restrict__ WT, int base)
{
    __shared__ float tile[64][65];
    const int mat = base + (int)blockIdx.z;
    const float* src;
    if (mat < 10) {
        const float* sel;
        switch (mat >> 1) {
            case 0: sel = Wq;  break;
            case 1: sel = Wq2; break;
            case 2: sel = Wk;  break;
            case 3: sel = Wk2; break;
            default: sel = Wv; break;
        }
        src = sel + (mat & 1) * 262144;
    } else {
        src = Wfc + (mat - 10) * 262144;
    }
    ushort* dst = WT + (size_t)blockIdx.z * 262144;

    const int tid = threadIdx.x;
    const int n0 = blockIdx.x * 64, k0 = blockIdx.y * 64;
    #pragma unroll
    for (int it = 0; it < 4; ++it) {
        int idx4 = tid + it * 256;            // 1024 float4 = 64k x 64n
        int kk = idx4 >> 4, c4 = (idx4 & 15) * 4;
        float4 v = ld4(src + (size_t)(k0 + kk) * 512 + n0 + c4);
        tile[kk][c4+0] = v.x; tile[kk][c4+1] = v.y;
        tile[kk][c4+2] = v.z; tile[kk][c4+3] = v.w;
    }
    __syncthreads();
    #pragma unroll
    for (int it = 0; it < 4; ++it) {
        int idx4 = tid + it * 256;            // n-major out
        int n = idx4 >> 4, c4 = (idx4 & 15) * 4;
        ushort4 o;
        o.x = f2bf(tile[c4+0][n]); o.y = f2bf(tile[c4+1][n]);
        o.z = f2bf(tile[c4+2][n]); o.w = f2bf(tile[c4+3][n]);
        *reinterpret_cast<ushort4*>(dst + (size_t)(n0 + n) * 512 + k0 + c4) = o;
    }
}

// ---------------------------------------------------------------------------
// K1/K6: projections + FC via MFMA. 128x128 tile, K-chunks of 64, 4 waves.
// A (fp32) staged+converted to bf16 in LDS; W^T (bf16, from cvt_w) staged.
// Fragment geometry (verified in scores_mfma R9): A-row=m at lane&15,
// B-row=n at lane&15, D: col=lane&15 (n), row=(lane>>4)*4+r (m).
// mode 0: qp/kp bf16 [bih][l][d]   mode 1: vpT bf16 [b8h][d][l*2+ens]
// mode 2: fcb fp32 [(m*2+ens)][n]
// ---------------------------------------------------------------------------
__global__ __launch_bounds__(256) void proj_mfma(
    const float* __restrict__ qin, const float* __restrict__ kin,
    const float* __restrict__ vin, const float* __restrict__ prebuf,
    const ushort* __restrict__ WT,
    ushort* __restrict__ qp, ushort* __restrict__ qp2, ushort* __restrict__ kp,
    ushort* __restrict__ kp2, ushort* __restrict__ vpT, float* __restrict__ fcb,
    int mm_base)
{
    __shared__ __align__(16) ushort At[128*64];   // [m][k] swizzled, 16KB
    __shared__ __align__(16) ushort Wt[128*64];   // [n][k] swizzled, 16KB

    const int z = blockIdx.z;
    const int mm = mm_base + z;
    const float* A; ushort* Du = nullptr; int ens; int mode;
    switch (mm) {
        case 0:  A=qin;    Du=qp;   ens=0; mode=0; break;
        case 1:  A=qin;    Du=qp;   ens=1; mode=0; break;
        case 2:  A=qin;    Du=qp2;  ens=0; mode=0; break;
        case 3:  A=qin;    Du=qp2;  ens=1; mode=0; break;
        case 4:  A=kin;    Du=kp;   ens=0; mode=0; break;
        case 5:  A=kin;    Du=kp;   ens=1; mode=0; break;
        case 6:  A=kin;    Du=kp2;  ens=0; mode=0; break;
        case 7:  A=kin;    Du=kp2;  ens=1; mode=0; break;
        case 8:  A=vin;    Du=vpT;  ens=0; mode=1; break;
        case 9:  A=vin;    Du=vpT;  ens=1; mode=1; break;
        case 10: A=prebuf;          ens=0; mode=2; break;
        default: A=prebuf;          ens=1; mode=2; break;
    }
    const ushort* wt = WT + (size_t)z * 262144;

    const int tid = threadIdx.x;
    const int m0 = blockIdx.y * 128;
    const int n0 = blockIdx.x * 128;
    const int wv = tid >> 6, lane = tid & 63;
    const int lr = lane & 15, kg = lane >> 4;

    f32x4 acc[2][8];
    #pragma unroll
    for (int qi = 0; qi < 2; ++qi)
        #pragma unroll
        for (int nt = 0; nt < 8; ++nt) acc[qi][nt] = (f32x4){0.f, 0.f, 0.f, 0.f};

    #pragma unroll 1
    for (int kc = 0; kc < 512; kc += 64) {
        __syncthreads();
        // stage A: 128m x 64k fp32 -> bf16, swizzled
        #pragma unroll
        for (int it = 0; it < 8; ++it) {
            int idx4 = tid + it * 256;            // 2048 float4
            int m = idx4 >> 4, c4 = (idx4 & 15) * 4;
            float4 v = ld4(A + (size_t)(m0 + m) * 1024 + ens * 512 + kc + c4);
            ushort4 o;
            o.x = f2bf(v.x); o.y = f2bf(v.y); o.z = f2bf(v.z); o.w = f2bf(v.w);
            int byte = m * 128 + c4 * 2; byte ^= (m & 7) << 4;
            *reinterpret_cast<ushort4*>((char*)At + byte) = o;
        }
        // stage W^T: 128n x 64k bf16, swizzled
        #pragma unroll
        for (int it = 0; it < 4; ++it) {
            int idx8 = tid + it * 256;            // 1024 x 16B
            int n = idx8 >> 3, c8 = idx8 & 7;
            int byte = n * 128 + c8 * 16; byte ^= (n & 7) << 4;
            *reinterpret_cast<uint4*>((char*)Wt + byte) =
                *reinterpret_cast<const uint4*>(wt + (size_t)(n0 + n) * 512 + kc + c8 * 8);
        }
        __syncthreads();

        s16x8 af[2][2];
        #pragma unroll
        for (int qi = 0; qi < 2; ++qi)
            #pragma unroll
            for (int ks = 0; ks < 2; ++ks) {
                int row = (wv*2 + qi)*16 + lr;
                int byte = row*128 + (ks*32 + kg*8)*2; byte ^= (row & 7) << 4;
                af[qi][ks] = *reinterpret_cast<const s16x8*>((const char*)At + byte);
            }
        #pragma unroll
        for (int nt = 0; nt < 8; ++nt) {
            int row = nt*16 + lr;
            int byte0 = row*128 + (kg*8)*2;      byte0 ^= (row & 7) << 4;
            int byte1 = row*128 + (32 + kg*8)*2; byte1 ^= (row & 7) << 4;
            s16x8 b0 = *reinterpret_cast<const s16x8*>((const char*)Wt + byte0);
            s16x8 b1 = *reinterpret_cast<const s16x8*>((const char*)Wt + byte1);
            #pragma unroll
            for (int qi = 0; qi < 2; ++qi) {
                acc[qi][nt] = __builtin_amdgcn_mfma_f32_16x16x32_bf16(af[qi][0], b0, acc[qi][nt], 0, 0, 0);
                acc[qi][nt] = __builtin_amdgcn_mfma_f32_16x16x32_bf16(af[qi][1], b1, acc[qi][nt], 0, 0, 0);
            }
        }
    }

    // epilogue: m = m0 + (wv*2+qi)*16 + kg*4 + r ; n = n0 + nt*16 + lr
    #pragma unroll
    for (int qi = 0; qi < 2; ++qi) {
        #pragma unroll
        for (int nt = 0; nt < 8; ++nt) {
            const int n = n0 + nt*16 + lr;
            const int hh = n >> 6, d = n & 63;
            #pragma unroll
            for (int r = 0; r < 4; ++r) {
                const int m = m0 + (wv*2 + qi)*16 + kg*4 + r;
                const int bb = m >> 8, l = m & 255;
                const float val = acc[qi][nt][r];
                if (mode == 0) {
                    Du[((size_t)((bb*2 + ens)*8 + hh) * 256 + l) * 64 + d] = f2bf(val);
                } else if (mode == 1) {
                    Du[(size_t)(bb*8 + hh) * 32768 + (size_t)d * 512 + l*2 + ens] = f2bf(val);
                } else {
                    fcb[((size_t)m*2 + ens) * 512 + n] = val;
                }
            }
        }
    }
}

// ---------------------------------------------------------------------------
// K2: gate MLP via MFMA (round-10 structure; finish uses __expf/__logf).
// ---------------------------------------------------------------------------
__global__ __launch_bounds__(256) void mlp_mfma(
    const float* __restrict__ gr_mask, const int* __restrict__ mask,
    const float* __restrict__ grW1, const float* __restrict__ grb1,
    const float* __restrict__ grW2, const float* __restrict__ grb2,
    float* __restrict__ scores)
{
    __shared__ __align__(16) ushort ts[256][40];
    __shared__ __align__(16) ushort w1b[32][16][32];
    __shared__ __align__(16) float  b1s[32][16];
    __shared__ __align__(16) float  w2s[32][16];
    __shared__ float b2s[32];
    __shared__ ushort ls[256][33];

    const int tid = threadIdx.x;
    const int bq = blockIdx.x;
    const int b = bq >> 8, q = bq & 255;

    unsigned* w1w = (unsigned*)&w1b[0][0][0];
    #pragma unroll
    for (int it = 0; it < 32; ++it) w1w[tid + it*256] = 0;
    unsigned* tsw = (unsigned*)&ts[0][0];
    #pragma unroll
    for (int it = 0; it < 8; ++it) {
        int flat = tid + it*256;
        tsw[(flat >> 3) * 20 + 8 + (flat & 7)] = 0;
    }
    __syncthreads();

    #pragma unroll
    for (int g = 0; g < 16; ++g)
        ts[tid][g] = f2bf(gr_mask[(size_t)(b*16 + g) * 65536 + q*256 + tid]);
    #pragma unroll
    for (int it = 0; it < 32; ++it) {
        int flat = tid + it*256;
        int c = flat >> 8, m = (flat >> 4) & 15, g = flat & 15;
        w1b[c][m][g] = f2bf(grW1[c*256 + g*16 + m]);
    }
    #pragma unroll
    for (int it = 0; it < 2; ++it) {
        int flat = tid + it*256;
        b1s[flat >> 4][flat & 15] = grb1[flat];
        w2s[flat >> 4][flat & 15] = grW2[flat];
    }
    if (tid < 32) b2s[tid] = grb2[tid];
    __syncthreads();

    const int wv = tid >> 6, lane = tid & 63;
    const int lr = lane & 15, mg = lane >> 4;

    s16x8 tf[4];
    #pragma unroll
    for (int lt = 0; lt < 4; ++lt) {
        int l = (wv*4 + lt)*16 + lr;
        tf[lt] = *reinterpret_cast<const s16x8*>(&ts[l][mg*8]);
    }

    #pragma unroll 1
    for (int c = 0; c < 32; ++c) {
        s16x8 af  = *reinterpret_cast<const s16x8*>(&w1b[c][lr][mg*8]);
        f32x4 b1v = *reinterpret_cast<const f32x4*>(&b1s[c][mg*4]);
        f32x4 w2v = *reinterpret_cast<const f32x4*>(&w2s[c][mg*4]);
        const float b2v = b2s[c];

        f32x4 acc[4];
        #pragma unroll
        for (int lt = 0; lt < 4; ++lt)
            acc[lt] = __builtin_amdgcn_mfma_f32_16x16x32_bf16(af, tf[lt], b1v, 0, 0, 0);

        #pragma unroll
        for (int lt = 0; lt < 4; ++lt) {
            float s = fmaxf(acc[lt][0], 0.f) * w2v[0];
            s = fmaf(fmaxf(acc[lt][1], 0.f), w2v[1], s);
            s = fmaf(fmaxf(acc[lt][2], 0.f), w2v[2], s);
            s = fmaf(fmaxf(acc[lt][3], 0.f), w2v[3], s);
            s += __shfl_xor(s, 16);
            s += __shfl_xor(s, 32);
            if (lane < 16)
                ls[(wv*4 + lt)*16 + lane][c] = f2bf(s + b2v);
        }
    }
    __syncthreads();

    const int mv = mask[(size_t)(b*256 + q)*256 + tid];
    #pragma unroll 1
    for (int c2 = 0; c2 < 32; ++c2) {
        float agv = bf2f(ls[tid][c2]);
        if (mv == 0) agv = 0.f;
        float lsig = fminf(agv, 0.f) - __logf(1.f + __expf(-fabsf(agv)));
        int ii = c2 >> 4, jj = (c2 >> 3) & 1, hh = c2 & 7;
        scores[((size_t)((b*2 + ii)*8 + hh)*256 + q)*512 + (size_t)tid*2 + jj] = lsig;
    }
}

// ---------------------------------------------------------------------------
// K3: scores via MFMA (unchanged, verified round 9).
// ---------------------------------------------------------------------------
__global__ __launch_bounds__(256) void scores_mfma(
    const ushort* __restrict__ qp, const ushort* __restrict__ qp2,
    const ushort* __restrict__ kp, const ushort* __restrict__ kp2,
    const float* __restrict__ adj, const int* __restrict__ mask,
    float* __restrict__ scores)
{
    __shared__ __align__(16) ushort q1t[128*64];
    __shared__ __align__(16) ushort q2t[128*64];
    __shared__ __align__(16) ushort k1t[128*64];
    __shared__ __align__(16) ushort k2t[128*64];

    const int z = blockIdx.z;
    const int bih = z >> 1, j = z & 1;
    const int b = bih >> 4, h = bih & 7;
    const int bjh = (b*2 + j)*8 + h;
    const int q0 = blockIdx.x * 128, k0 = blockIdx.y * 128;
    const int tid = threadIdx.x;

    const ushort* gq1 = qp  + (size_t)bih * 16384 + q0 * 64;
    const ushort* gq2 = qp2 + (size_t)bih * 16384 + q0 * 64;
    const ushort* gk1 = kp  + (size_t)bjh * 16384 + k0 * 64;
    const ushort* gk2 = kp2 + (size_t)bjh * 16384 + k0 * 64;
    #pragma unroll
    for (int it = 0; it < 4; ++it) {
        int ch = tid + it * 256;
        int row = ch >> 3, c8 = ch & 7;
        int byte = row * 128 + c8 * 16; byte ^= (row & 7) << 4;
        *reinterpret_cast<uint4*>((char*)q1t + byte) = *reinterpret_cast<const uint4*>(gq1 + ch*8);
        *reinterpret_cast<uint4*>((char*)q2t + byte) = *reinterpret_cast<const uint4*>(gq2 + ch*8);
        *reinterpret_cast<uint4*>((char*)k1t + byte) = *reinterpret_cast<const uint4*>(gk1 + ch*8);
        *reinterpret_cast<uint4*>((char*)k2t + byte) = *reinterpret_cast<const uint4*>(gk2 + ch*8);
    }
    __syncthreads();

    const int wv = tid >> 6, lane = tid & 63;
    const int lr = lane & 15, kg = lane >> 4;

    #pragma unroll 1
    for (int qi = 0; qi < 2; ++qi) {
        const int qt = wv * 2 + qi;
        s16x8 a1[2], a2[2];
        #pragma unroll
        for (int ks = 0; ks < 2; ++ks) {
            int row = qt*16 + lr;
            int byte = row*128 + (ks*32 + kg*8)*2; byte ^= (row & 7) << 4;
            a1[ks] = *reinterpret_cast<const s16x8*>((const char*)q1t + byte);
            a2[ks] = *reinterpret_cast<const s16x8*>((const char*)q2t + byte);
        }
        #pragma unroll 1
        for (int kt = 0; kt < 8; ++kt) {
            f32x4 acc1 = {0.f, 0.f, 0.f, 0.f};
            f32x4 acc2 = {0.f, 0.f, 0.f, 0.f};
            #pragma unroll
            for (int ks = 0; ks < 2; ++ks) {
                int row = kt*16 + lr;
                int byte = row*128 + (ks*32 + kg*8)*2; byte ^= (row & 7) << 4;
                s16x8 b1 = *reinterpret_cast<const s16x8*>((const char*)k1t + byte);
                s16x8 b2 = *reinterpret_cast<const s16x8*>((const char*)k2t + byte);
                acc1 = __builtin_amdgcn_mfma_f32_16x16x32_bf16(a1[ks], b1, acc1, 0, 0, 0);
                acc2 = __builtin_amdgcn_mfma_f32_16x16x32_bf16(a2[ks], b2, acc2, 0, 0, 0);
            }
            const int kgl = k0 + kt*16 + lr;
            #pragma unroll
            for (int r = 0; r < 4; ++r) {
                const int qg = q0 + qt*16 + kg*4 + r;
                const size_t mi = (size_t)(b*256 + qg) * 256 + kgl;
                float gate = (qg >= kgl) ? adj[mi] : 0.f;
                float s = (acc1[r]*gate + acc2[r]*(1.f - gate)) * 0.125f;
                const size_t sidx = ((size_t)bih * 256 + qg) * 512 + (size_t)kgl * 2 + j;
                s += scores[sidx];
                if (mask[mi] == 0) s = -1e9f;
                scores[sidx] = s;
            }
        }
    }
}

// ---------------------------------------------------------------------------
// K4: softmax over 512 per row; also emits bf16 attn copy for MFMA PV.
// ---------------------------------------------------------------------------
__global__ __launch_bounds__(256) void softmax_k(float* __restrict__ scores,
                                                 ushort* __restrict__ attn_bf)
{
    const int row  = blockIdx.x * 4 + (threadIdx.x >> 6);
    const int lane = threadIdx.x & 63;
    float* p = scores + (size_t)row * 512 + lane * 8;
    float4 v0 = *reinterpret_cast<float4*>(p);
    float4 v1 = *reinterpret_cast<float4*>(p + 4);
    float v[8] = {v0.x, v0.y, v0.z, v0.w, v1.x, v1.y, v1.z, v1.w};

    float m = v[0];
    #pragma unroll
    for (int t = 1; t < 8; ++t) m = fmaxf(m, v[t]);
    #pragma unroll
    for (int off = 32; off > 0; off >>= 1) m = fmaxf(m, __shfl_xor(m, off));

    float s = 0.f;
    #pragma unroll
    for (int t = 0; t < 8; ++t) { v[t] = expf(v[t] - m); s += v[t]; }
    #pragma unroll
    for (int off = 32; off > 0; off >>= 1) s += __shfl_xor(s, off);

    const float inv = 1.f / s;
    #pragma unroll
    for (int t = 0; t < 8; ++t) v[t] *= inv;
    *reinterpret_cast<float4*>(p)     = make_float4(v[0], v[1], v[2], v[3]);
    *reinterpret_cast<float4*>(p + 4) = make_float4(v[4], v[5], v[6], v[7]);

    ushort* pb = attn_bf + (size_t)row * 512 + lane * 8;
    ushort4 lo, hi;
    lo.x = f2bf(v[0]); lo.y = f2bf(v[1]); lo.z = f2bf(v[2]); lo.w = f2bf(v[3]);
    hi.x = f2bf(v[4]); hi.y = f2bf(v[5]); hi.z = f2bf(v[6]); hi.w = f2bf(v[7]);
    *reinterpret_cast<ushort4*>(pb)     = lo;
    *reinterpret_cast<ushort4*>(pb + 4) = hi;
}

// ---------------------------------------------------------------------------
// K5: PV via MFMA (unchanged, verified round 9).
// ---------------------------------------------------------------------------
__global__ __launch_bounds__(256) void pv_mfma(
    const ushort* __restrict__ attn, const ushort* __restrict__ vpT,
    float* __restrict__ pre)
{
    __shared__ __align__(16) ushort at_t[64*128];
    __shared__ __align__(16) ushort v_t[64*128];

    const int bih = blockIdx.y;
    const int b = bih >> 4, i = (bih >> 3) & 1, h = bih & 7;
    const int q0 = blockIdx.x * 64;
    const int tid = threadIdx.x;
    const int wv = tid >> 6, lane = tid & 63;
    const int lr = lane & 15, kg = lane >> 4;

    const ushort* ga = attn + ((size_t)bih * 256 + q0) * 512;
    const ushort* gv = vpT + (size_t)(b*8 + h) * 32768;

    f32x4 acc[4];
    #pragma unroll
    for (int dt = 0; dt < 4; ++dt) acc[dt] = (f32x4){0.f, 0.f, 0.f, 0.f};

    #pragma unroll 1
    for (int kc = 0; kc < 4; ++kc) {
        __syncthreads();
        #pragma unroll
        for (int it = 0; it < 4; ++it) {
            int ch = tid + it * 256;
            int row = ch >> 4, c8 = ch & 15;
            int byte = row * 256 + c8 * 16; byte ^= (row & 7) << 4;
            *reinterpret_cast<uint4*>((char*)at_t + byte) =
                *reinterpret_cast<const uint4*>(ga + (size_t)row*512 + kc*128 + c8*8);
            *reinterpret_cast<uint4*>((char*)v_t + byte) =
                *reinterpret_cast<const uint4*>(gv + (size_t)row*512 + kc*128 + c8*8);
        }
        __syncthreads();
        #pragma unroll
        for (int ks = 0; ks < 4; ++ks) {
            int arow = wv*16 + lr;
            int abyte = arow*256 + (ks*32 + kg*8)*2; abyte ^= (arow & 7) << 4;
            s16x8 a = *reinterpret_cast<const s16x8*>((const char*)at_t + abyte);
            #pragma unroll
            for (int dt = 0; dt < 4; ++dt) {
                int vrow = dt*16 + lr;
                int vbyte = vrow*256 + (ks*32 + kg*8)*2; vbyte ^= (vrow & 7) << 4;
                s16x8 bv = *reinterpret_cast<const s16x8*>((const char*)v_t + vbyte);
                acc[dt] = __builtin_amdgcn_mfma_f32_16x16x32_bf16(a, bv, acc[dt], 0, 0, 0);
            }
        }
    }

    #pragma unroll
    for (int dt = 0; dt < 4; ++dt) {
        const int d = dt*16 + lr;
        #pragma unroll
        for (int r = 0; r < 4; ++r) {
            const int qg = q0 + wv*16 + kg*4 + r;
            pre[((size_t)(b*256 + qg)*2 + i) * 512 + h*64 + d] = acc[dt][r];
        }
    }
}

// ---------------------------------------------------------------------------
// K7: residual + LayerNorm over D=512. One block per (b,q,i) row.
// ---------------------------------------------------------------------------
__global__ __launch_bounds__(256) void ln_k(
    const float* __restrict__ fcb, const float* __restrict__ qin,
    const float* __restrict__ lng, const float* __restrict__ lnb,
    float* __restrict__ out)
{
    __shared__ float red[8];
    const int row = blockIdx.x;
    const int tid = threadIdx.x;
    const float* fr = fcb + (size_t)row * 512;
    const float* qr = qin + (size_t)row * 512;
    float v0 = fr[tid]       + qr[tid];
    float v1 = fr[tid + 256] + qr[tid + 256];
    float s  = v0 + v1;
    float sq = v0*v0 + v1*v1;
    #pragma unroll
    for (int off = 32; off > 0; off >>= 1) {
        s  += __shfl_xor(s, off);
        sq += __shfl_xor(sq, off);
    }
    const int w = tid >> 6;
    if ((tid & 63) == 0) { red[w*2] = s; red[w*2 + 1] = sq; }
    __syncthreads();
    s  = red[0] + red[2] + red[4] + red[6];
    sq = red[1] + red[3] + red[5] + red[7];
    const float mu  = s * (1.f / 512.f);
    const float var = sq * (1.f / 512.f) - mu * mu;
    const float rs  = rsqrtf(var + 1e-6f);
    out[(size_t)row * 512 + tid]       = (v0 - mu) * rs * lng[tid]       + lnb[tid];
    out[(size_t)row * 512 + tid + 256] = (v1 - mu) * rs * lng[tid + 256] + lnb[tid + 256];
}

// ---------------------------------------------------------------------------
extern "C" void kernel_launch(void* const* d_in, const int* in_sizes, int n_in,
                              void* d_out, int out_size, void* d_ws, size_t ws_size,
                              hipStream_t stream) {
    (void)in_sizes; (void)n_in; (void)out_size; (void)ws_size;
    const float* qin    = (const float*)d_in[0];
    const float* kin    = (const float*)d_in[1];
    const float* vin    = (const float*)d_in[2];
    const int*   maskp  = (const int*)  d_in[3];
    const float* grm    = (const float*)d_in[4];
    const float* adj    = (const float*)d_in[5];
    const float* Wq     = (const float*)d_in[6];
    const float* Wk     = (const float*)d_in[7];
    const float* Wv     = (const float*)d_in[8];
    const float* Wq2    = (const float*)d_in[9];
    const float* Wk2    = (const float*)d_in[10];
    const float* Wfc    = (const float*)d_in[12];
    const float* grW1   = (const float*)d_in[13];
    const float* grb1   = (const float*)d_in[14];
    const float* grW2   = (const float*)d_in[15];
    const float* grb2   = (const float*)d_in[16];
    const float* lng    = (const float*)d_in[17];
    const float* lnb    = (const float*)d_in[18];
    float* out = (float*)d_out;

    char* w = (char*)d_ws;
    const size_t MB = 1048576;
    float*  scores  = (float*)(w);
    ushort* attn_bf = (ushort*)(w + 32*MB);
    ushort* WT      = (ushort*)(w + 32*MB);   // aliases attn_bf (dead windows)
    float*  pre     = (float*) (w + 48*MB);
    ushort* qp_bf   = (ushort*)(w + 52*MB);
    ushort* qp2_bf  = (ushort*)(w + 54*MB);
    ushort* kp_bf   = (ushort*)(w + 56*MB);
    ushort* kp2_bf  = (ushort*)(w + 58*MB);
    ushort* vpT     = (ushort*)(w + 60*MB);
    float*  fcb     = (float*) (w + 52*MB);   // alias: qp_bf/qp2_bf dead by FC

    // 0) weight transpose+cvt for the 10 projection matrices -> WT @32M
    cvt_w<<<dim3(8, 8, 10), 256, 0, stream>>>(Wq, Wq2, Wk, Wk2, Wv, Wfc, WT, 0);
    // 1) projections via MFMA -> qp/qp2/kp/kp2 [bih][l][d], vpT [b8h][d][ke]
    proj_mfma<<<dim3(4, 8, 10), 256, 0, stream>>>(qin, kin, vin, pre, WT,
                                                  qp_bf, qp2_bf, kp_bf, kp2_bf,
                                                  vpT, fcb, 0);
    // 2) gate MLP via MFMA -> log_sigmoid staged into scores
    mlp_mfma<<<1024, 256, 0, stream>>>(grm, maskp, grW1, grb1, grW2, grb2, scores);
    // 3) scores via MFMA (QK^T gate + staged lsig + mask)
    scores_mfma<<<dim3(2, 2, 128), 256, 0, stream>>>(qp_bf, qp2_bf, kp_bf, kp2_bf,
                                                     adj, maskp, scores);
    // 4) softmax (+ bf16 attn copy)
    softmax_k<<<4096, 256, 0, stream>>>(scores, attn_bf);
    // 5) attn @ V via MFMA -> pre (fp32)
    pv_mfma<<<dim3(4, 64), 256, 0, stream>>>(attn_bf, vpT, pre);
    // 5.5) Wfc transpose+cvt -> WT @32M (attn_bf dead after pv)
    cvt_w<<<dim3(8, 8, 2), 256, 0, stream>>>(Wq, Wq2, Wk, Wk2, Wv, Wfc, WT, 10);
    // 6) FC via MFMA (A = pre fp32, cvt in-kernel) -> fcb fp32
    proj_mfma<<<dim3(4, 8, 2), 256, 0, stream>>>(qin, kin, vin, pre, WT,
                                                 qp_bf, qp2_bf, kp_bf, kp2_bf,
                                                 vpT, fcb, 10);
    // 7) residual + LayerNorm
    ln_k<<<2048, 256, 0, stream>>>(fcb, qin, lng, lnb, out);
}